// Round 12
// baseline (154.989 us; speedup 1.0000x reference)
//
#include <hip/hip_runtime.h>
#include <hip/hip_bf16.h>

#define NB 8
#define NC 256
#define NHW 4096       // H*W
#define HDIM 64
#define WDIM 64
#define NHEAD 8
#define NKD 32
#define NAG 64
#define NMIP 8
#define NSPLIT 16
#define EPSF 1e-5f
#define FSCALE 0.17677669529663687f  // 32^-0.5
#define SZQ ((size_t)NB * NC * NHW)

typedef __attribute__((ext_vector_type(8))) short bf16x8;
typedef __attribute__((ext_vector_type(8))) unsigned short u16x8;
typedef __attribute__((ext_vector_type(4))) unsigned short u16x4;
typedef __attribute__((ext_vector_type(4))) float f32x4;

__device__ __forceinline__ unsigned short f2bf(float f) {
    union { float f; unsigned u; } v; v.f = f;
    unsigned r = v.u + 0x7FFF + ((v.u >> 16) & 1);
    return (unsigned short)(r >> 16);
}
__device__ __forceinline__ float b2f(unsigned short u) {
    union { unsigned u32; float f; } v; v.u32 = ((unsigned)u) << 16; return v.f;
}
__device__ __forceinline__ void gload_lds16(const unsigned short* g, unsigned short* l) {
    __builtin_amdgcn_global_load_lds(
        (const __attribute__((address_space(1))) unsigned int*)g,
        (__attribute__((address_space(3))) unsigned int*)l, 16, 0, 0);
}

// ---------------- K0a: transpose+convert x -> xbt[b][n][c] bf16 ----------------
__global__ __launch_bounds__(256) void k_xpose(const float* __restrict__ x,
                                               unsigned short* __restrict__ xbt) {
    const int b = blockIdx.y;
    const int n0 = blockIdx.x * 64;
    const int tid = threadIdx.x;
    __shared__ unsigned short lt[64 * 258];   // [n][c], pad 2

    #pragma unroll
    for (int it = 0; it < 4; ++it) {
        int c = it * 64 + (tid >> 2);
        int nq = (tid & 3) * 16;
        const float* xp = x + ((size_t)b * NC + c) * NHW + n0 + nq;
        float4 v0 = reinterpret_cast<const float4*>(xp)[0];
        float4 v1 = reinterpret_cast<const float4*>(xp)[1];
        float4 v2 = reinterpret_cast<const float4*>(xp)[2];
        float4 v3 = reinterpret_cast<const float4*>(xp)[3];
        float t[16] = {v0.x,v0.y,v0.z,v0.w, v1.x,v1.y,v1.z,v1.w,
                       v2.x,v2.y,v2.z,v2.w, v3.x,v3.y,v3.z,v3.w};
        #pragma unroll
        for (int i = 0; i < 16; ++i)
            lt[(nq + i) * 258 + c] = f2bf(t[i]);
    }
    __syncthreads();

    const int n = tid >> 2, cq = tid & 3;
    unsigned short* dst = xbt + ((size_t)b * NHW + n0 + n) * NC + cq * 64;
    #pragma unroll
    for (int v = 0; v < 8; ++v) {
        union { unsigned short u[8]; u16x8 w; } pk;
        #pragma unroll
        for (int i = 0; i < 8; ++i)
            pk.u[i] = lt[n * 258 + cq * 64 + v * 8 + i];
        *reinterpret_cast<u16x8*>(dst + v * 8) = pk.w;
    }
}

// ---------------- K0b: pre-convert w_qkv and w_proj to bf16 ----------------
__global__ __launch_bounds__(256) void k_wcast(const float* __restrict__ wq,
                                               const float* __restrict__ wp,
                                               unsigned short* __restrict__ wqb,
                                               unsigned short* __restrict__ wpb) {
    const int i = (blockIdx.x * 256 + threadIdx.x) * 4;
    const int NQ = 768 * 256;
    if (i < NQ) {
        float4 v = *reinterpret_cast<const float4*>(wq + i);
        u16x4 u = {f2bf(v.x), f2bf(v.y), f2bf(v.z), f2bf(v.w)};
        *reinterpret_cast<u16x4*>(wqb + i) = u;
    } else {
        int j = i - NQ;
        float4 v = *reinterpret_cast<const float4*>(wp + j);
        u16x4 u = {f2bf(v.x), f2bf(v.y), f2bf(v.z), f2bf(v.w)};
        *reinterpret_cast<u16x4*>(wpb + j) = u;
    }
}

// ---------------- K1: qkv = BN(wb @ xbt), bf16 MFMA, gload_lds + coalesced epilogue ----------------
// grid (32, 6, 8); 256 thr = 4 waves (2x2), 128x128 tile, BK=32
__global__ __launch_bounds__(256) void k_qkv(const unsigned short* __restrict__ xbt,
                                             const unsigned short* __restrict__ wb,
                                             const float* __restrict__ bnp,
                                             unsigned short* __restrict__ Qb,
                                             unsigned short* __restrict__ Kb,
                                             unsigned short* __restrict__ Vb) {
    const int b   = blockIdx.z;
    const int ocB = blockIdx.y * 128;
    const int nB  = blockIdx.x * 128;
    const int tid = threadIdx.x;
    const int wv  = tid >> 6, lane = tid & 63;
    const int wm = wv >> 1, wn = wv & 1;
    const int lm = lane & 15, lg = lane >> 4;

    __shared__ __align__(16) unsigned short S[8192];   // As | Bs, reused as epilogue buf
    unsigned short* As = S;
    unsigned short* Bs = S + 4096;

    f32x4 acc[4][4];
    #pragma unroll
    for (int i = 0; i < 4; ++i)
        #pragma unroll
        for (int j = 0; j < 4; ++j)
            acc[i][j] = (f32x4){0.f, 0.f, 0.f, 0.f};

    const int srow = lane >> 2;
    const int kl = ((lane & 3) ^ ((lane >> 3) & 3)) * 8;   // pre-swizzled source chunk
    const size_t agbase = (size_t)(ocB + wv * 32 + srow) * 256 + kl;
    const size_t bgbase = ((size_t)b * NHW + nB + wv * 32 + srow) * NC + kl;
    const int sw = (lm >> 1) & 3;                          // read-side XOR

    for (int k0 = 0; k0 < 256; k0 += 32) {
        #pragma unroll
        for (int j = 0; j < 2; ++j) {
            gload_lds16(wb + agbase + (size_t)j * 16 * 256 + k0, &As[wv * 1024 + j * 512]);
            gload_lds16(xbt + bgbase + (size_t)j * 16 * NC + k0, &Bs[wv * 1024 + j * 512]);
        }
        __syncthreads();

        bf16x8 af[4], bfr[4];
        #pragma unroll
        for (int mi = 0; mi < 4; ++mi)
            af[mi] = *reinterpret_cast<const bf16x8*>(&As[(wm * 64 + mi * 16 + lm) * 32 + (lg ^ sw) * 8]);
        #pragma unroll
        for (int ni = 0; ni < 4; ++ni)
            bfr[ni] = *reinterpret_cast<const bf16x8*>(&Bs[(wn * 64 + ni * 16 + lm) * 32 + (lg ^ sw) * 8]);
        #pragma unroll
        for (int mi = 0; mi < 4; ++mi)
            #pragma unroll
            for (int ni = 0; ni < 4; ++ni)
                acc[mi][ni] = __builtin_amdgcn_mfma_f32_16x16x32_bf16(af[mi], bfr[ni], acc[mi][ni], 0, 0, 0);
        __syncthreads();
    }

    // epilogue: 4 chunks of 32 oc-rows through LDS, coalesced u16x8 stores
    for (int ch = 0; ch < 4; ++ch) {
        if (wm == (ch >> 1)) {
            #pragma unroll
            for (int mq = 0; mq < 2; ++mq) {
                int mi = (ch & 1) * 2 + mq;
                #pragma unroll
                for (int r = 0; r < 4; ++r) {
                    int rloc = mi * 16 + lg * 4 + r - (ch & 1) * 32;   // 0..31
                    int oc = ocB + ch * 32 + rloc;
                    float g = bnp[0 * 768 + oc], be = bnp[1 * 768 + oc];
                    float m = bnp[2 * 768 + oc], vv = bnp[3 * 768 + oc];
                    float inv = g * rsqrtf(vv + EPSF);
                    float bias = be - m * inv;
                    #pragma unroll
                    for (int ni = 0; ni < 4; ++ni)
                        S[rloc * 136 + wn * 64 + ni * 16 + lm] = f2bf(acc[mi][ni][r] * inv + bias);
                }
            }
        }
        __syncthreads();
        {
            int ocb2 = ocB + ch * 32;
            unsigned short* base; int oc2base;
            if (ocb2 < 256)      { base = Qb; oc2base = ocb2; }
            else if (ocb2 < 512) { base = Kb; oc2base = ocb2 - 256; }
            else                 { base = Vb; oc2base = ocb2 - 512; }
            #pragma unroll
            for (int j = 0; j < 2; ++j) {
                int i = tid + 256 * j;
                int row = i >> 4, sg = i & 15;
                u16x8 v = *reinterpret_cast<const u16x8*>(&S[row * 136 + sg * 8]);
                *reinterpret_cast<u16x8*>(base + ((size_t)b * NC + oc2base + row) * NHW + nB + sg * 8) = v;
            }
        }
        __syncthreads();
    }
}

// ---------------- K2a: per-(b,c,h) W-means of K and V ----------------
__global__ __launch_bounds__(256) void k_means(const unsigned short* __restrict__ K,
                                               const unsigned short* __restrict__ V,
                                               float* __restrict__ AMK,
                                               float* __restrict__ AMV) {
    const int bc = blockIdx.x;
    const int b = bc >> 8;
    const int c = bc & 255;
    const int t = threadIdx.x;
    #pragma unroll
    for (int pass = 0; pass < 2; ++pass) {
        const unsigned short* p = (pass ? V : K) + (size_t)bc * NHW + t * 16;
        u16x8 a0 = *reinterpret_cast<const u16x8*>(p);
        u16x8 a1 = *reinterpret_cast<const u16x8*>(p + 8);
        float s = 0.f;
        #pragma unroll
        for (int i = 0; i < 8; ++i) s += b2f(a0[i]);
        #pragma unroll
        for (int i = 0; i < 8; ++i) s += b2f(a1[i]);
        s += __shfl_xor(s, 1);
        s += __shfl_xor(s, 2);
        if ((t & 3) == 0)
            (pass ? AMV : AMK)[((size_t)b * HDIM + (t >> 2)) * NC + c] = s * (1.0f / 64.0f);
    }
}

// ---------------- K2b: SE gate values per (b,h) ----------------
__global__ __launch_bounds__(256) void k_gatecomp(const float* __restrict__ AMK,
                                                  const float* __restrict__ AMV,
                                                  const float* __restrict__ w1,
                                                  const float* __restrict__ bn1,
                                                  const float* __restrict__ w2,
                                                  const float* __restrict__ bn2,
                                                  float* __restrict__ GK,
                                                  float* __restrict__ GV) {
    const int b = blockIdx.x >> 6;
    const int h = blockIdx.x & 63;
    const int c = threadIdx.x;
    __shared__ float am[NC];
    __shared__ float m1[NMIP];
    for (int pass = 0; pass < 2; ++pass) {
        am[c] = (pass ? AMV : AMK)[((size_t)b * HDIM + h) * NC + c];
        __syncthreads();
        if (c < NMIP) {
            float t = 0.f;
            for (int cc = 0; cc < NC; ++cc) t += w1[c * NC + cc] * am[cc];
            float g = bn1[0 * NMIP + c], be = bn1[1 * NMIP + c];
            float mm = bn1[2 * NMIP + c], vv = bn1[3 * NMIP + c];
            float inv = g * rsqrtf(vv + EPSF);
            m1[c] = t * inv + (be - mm * inv);
        }
        __syncthreads();
        {
            float t = 0.f;
            #pragma unroll
            for (int j = 0; j < NMIP; ++j) t += w2[c * NMIP + j] * m1[j];
            float g = bn2[0 * NC + c], be = bn2[1 * NC + c];
            float mm = bn2[2 * NC + c], vv = bn2[3 * NC + c];
            float inv = g * rsqrtf(vv + EPSF);
            (pass ? GV : GK)[((size_t)b * NC + c) * HDIM + h] = t * inv + (be - mm * inv);
        }
        __syncthreads();
    }
}

// ---------------- K3: 8x8 block pool of Q -> agent tokens ----------------
__global__ __launch_bounds__(64) void k_pool(const unsigned short* __restrict__ Q,
                                             float* __restrict__ A_) {
    const int bc = blockIdx.x;
    const int ag = threadIdx.x;
    const int ph = ag >> 3, pw = ag & 7;
    const unsigned short* src = Q + (size_t)bc * NHW;
    float s = 0.f;
    #pragma unroll
    for (int i = 0; i < 8; ++i) {
        u16x8 v = *reinterpret_cast<const u16x8*>(&src[(ph * 8 + i) * WDIM + pw * 8]);
        #pragma unroll
        for (int j = 0; j < 8; ++j) s += b2f(v[j]);
    }
    A_[(size_t)bc * NAG + ag] = s * (1.0f / 64.0f);
}

// ---------------- K4a: agent attn partials (split-N flash), bf16 MFMA, gate-fused ----------------
__global__ __launch_bounds__(256) void k_attn_part(const unsigned short* __restrict__ K,
                                                   const unsigned short* __restrict__ V,
                                                   const float* __restrict__ A_,
                                                   const float* __restrict__ GK,
                                                   const float* __restrict__ GV,
                                                   float* __restrict__ Pm,
                                                   float* __restrict__ Pl,
                                                   float* __restrict__ Pacc) {
    const int bh = blockIdx.x >> 4;
    const int ns = blockIdx.x & (NSPLIT - 1);
    const int b = bh >> 3, h = bh & 7;
    const int tid = threadIdx.x;
    const int wv = tid >> 6, lane = tid & 63;
    const int lm = lane & 15, lg = lane >> 4;

    __shared__ unsigned short a_s[64 * 40];   // [ag][d]
    __shared__ unsigned short kt_s[64 * 40];  // [col][d]
    __shared__ unsigned short vt_s[32 * 72];  // [dd][col]
    __shared__ unsigned short Ps[64 * 72];    // [ag][col]

    {
        int d = tid >> 3, ag0 = (tid & 7) * 8;
        const float* ap = A_ + ((size_t)(b * NC + h * NKD + d)) * NAG + ag0;
        float4 v0 = reinterpret_cast<const float4*>(ap)[0];
        float4 v1 = reinterpret_cast<const float4*>(ap)[1];
        float t8[8] = {v0.x, v0.y, v0.z, v0.w, v1.x, v1.y, v1.z, v1.w};
        #pragma unroll
        for (int i = 0; i < 8; ++i)
            a_s[(ag0 + i) * 40 + d] = f2bf(t8[i] * FSCALE);
    }

    float mrow[4], lrow[4];
    f32x4 acc[2];
    #pragma unroll
    for (int r = 0; r < 4; ++r) { mrow[r] = -1e30f; lrow[r] = 0.f; }
    acc[0] = (f32x4){0.f, 0.f, 0.f, 0.f};
    acc[1] = (f32x4){0.f, 0.f, 0.f, 0.f};

    const int colbase = ns * (NHW / NSPLIT);
    const unsigned short* Kp = K + (size_t)(b * NC + h * NKD) * NHW + colbase;
    const unsigned short* Vp = V + (size_t)(b * NC + h * NKD) * NHW + colbase;
    const int sd = tid >> 3;
    const size_t gbase = ((size_t)(b * NC + h * NKD + sd)) * HDIM;
    __syncthreads();

    for (int nt = 0; nt < 4; ++nt) {
        const int gh = ns * 4 + nt;
        {
            int c0 = tid & 7;
            float gk = GK[gbase + gh];
            const unsigned short* kp = Kp + (size_t)sd * NHW + nt * 64 + c0;
            #pragma unroll
            for (int i = 0; i < 8; ++i)
                kt_s[(c0 + 8 * i) * 40 + sd] = f2bf(b2f(kp[8 * i]) * gk);
        }
        {
            int c0 = (tid & 7) * 8;
            float gv = GV[gbase + gh];
            const unsigned short* vp = Vp + (size_t)sd * NHW + nt * 64 + c0;
            u16x8 vr = *reinterpret_cast<const u16x8*>(vp);
            union { unsigned short u[8]; u16x8 v; } pk;
            #pragma unroll
            for (int i = 0; i < 8; ++i) pk.u[i] = f2bf(b2f(vr[i]) * gv);
            *reinterpret_cast<u16x8*>(&vt_s[sd * 72 + c0]) = pk.v;
        }
        __syncthreads();

        f32x4 s[4];
        {
            bf16x8 af = *reinterpret_cast<const bf16x8*>(&a_s[(wv * 16 + lm) * 40 + lg * 8]);
            #pragma unroll
            for (int ni = 0; ni < 4; ++ni) {
                bf16x8 kf = *reinterpret_cast<const bf16x8*>(&kt_s[(ni * 16 + lm) * 40 + lg * 8]);
                s[ni] = __builtin_amdgcn_mfma_f32_16x16x32_bf16(
                    af, kf, (f32x4){0.f, 0.f, 0.f, 0.f}, 0, 0, 0);
            }
        }

        float fsc[4];
        #pragma unroll
        for (int r = 0; r < 4; ++r) {
            float mx = fmaxf(fmaxf(s[0][r], s[1][r]), fmaxf(s[2][r], s[3][r]));
            mx = fmaxf(mx, __shfl_xor(mx, 1));
            mx = fmaxf(mx, __shfl_xor(mx, 2));
            mx = fmaxf(mx, __shfl_xor(mx, 4));
            mx = fmaxf(mx, __shfl_xor(mx, 8));
            float mnew = fmaxf(mrow[r], mx);
            fsc[r] = __expf(mrow[r] - mnew);
            mrow[r] = mnew;
            int agrow = wv * 16 + lg * 4 + r;
            float ps = 0.f;
            #pragma unroll
            for (int ni = 0; ni < 4; ++ni) {
                float p = __expf(s[ni][r] - mnew);
                Ps[agrow * 72 + ni * 16 + lm] = f2bf(p);
                ps += p;
            }
            ps += __shfl_xor(ps, 1);
            ps += __shfl_xor(ps, 2);
            ps += __shfl_xor(ps, 4);
            ps += __shfl_xor(ps, 8);
            lrow[r] = lrow[r] * fsc[r] + ps;
        }
        #pragma unroll
        for (int ni = 0; ni < 2; ++ni)
            #pragma unroll
            for (int r = 0; r < 4; ++r)
                acc[ni][r] *= fsc[r];
        __syncthreads();

        #pragma unroll
        for (int kk = 0; kk < 2; ++kk) {
            bf16x8 pa = *reinterpret_cast<const bf16x8*>(&Ps[(wv * 16 + lm) * 72 + kk * 32 + lg * 8]);
            #pragma unroll
            for (int ni = 0; ni < 2; ++ni) {
                bf16x8 vb = *reinterpret_cast<const bf16x8*>(&vt_s[(ni * 16 + lm) * 72 + kk * 32 + lg * 8]);
                acc[ni] = __builtin_amdgcn_mfma_f32_16x16x32_bf16(pa, vb, acc[ni], 0, 0, 0);
            }
        }
        __syncthreads();
    }

    const size_t pbase = (size_t)(bh * NSPLIT + ns) * NAG;
    #pragma unroll
    for (int r = 0; r < 4; ++r) {
        int ag = wv * 16 + lg * 4 + r;
        #pragma unroll
        for (int ni = 0; ni < 2; ++ni)
            Pacc[(pbase + ag) * NKD + ni * 16 + lm] = acc[ni][r];
        if (lm == 0) {
            Pm[pbase + ag] = mrow[r];
            Pl[pbase + ag] = lrow[r];
        }
    }
}

// ---------------- K4b: combine partials ----------------
__global__ __launch_bounds__(256) void k_attn_comb(const float* __restrict__ Pm,
                                                   const float* __restrict__ Pl,
                                                   const float* __restrict__ Pacc,
                                                   float* __restrict__ AT) {
    const int bh = blockIdx.x;
    const int tid = threadIdx.x;
    const int ag = tid >> 2, jg = tid & 3;
    float m = -1e30f;
    #pragma unroll
    for (int ns = 0; ns < NSPLIT; ++ns)
        m = fmaxf(m, Pm[(size_t)(bh * NSPLIT + ns) * NAG + ag]);
    float l = 0.f;
    float acc[8] = {};
    for (int ns = 0; ns < NSPLIT; ++ns) {
        size_t pb = (size_t)(bh * NSPLIT + ns) * NAG + ag;
        float f = __expf(Pm[pb] - m);
        l += Pl[pb] * f;
        const float* pp = Pacc + pb * NKD + jg * 8;
        #pragma unroll
        for (int i = 0; i < 8; ++i) acc[i] += pp[i] * f;
    }
    float linv = 1.0f / l;
    #pragma unroll
    for (int i = 0; i < 8; ++i)
        AT[((size_t)bh * NAG + ag) * NKD + jg * 8 + i] = acc[i] * linv;
}

// ---------------- K5: out1 = softmax_ag(q^T a) @ attn, bf16 MFMA, writes O1t[n][c] ----------------
__global__ __launch_bounds__(256) void k_qattn(const unsigned short* __restrict__ Q,
                                               const float* __restrict__ A_,
                                               const float* __restrict__ AT,
                                               unsigned short* __restrict__ O1t) {
    const int bh = blockIdx.y;
    const int b = bh >> 3, h = bh & 7;
    const int n0 = blockIdx.x * 128;
    const int tid = threadIdx.x;
    const int wv = tid >> 6, lane = tid & 63;
    const int lm = lane & 15, lg = lane >> 4;

    __shared__ unsigned short Qs[128][40];
    __shared__ unsigned short Ags[64][40];
    __shared__ unsigned short ATs[32][72];
    __shared__ unsigned short Ps[128][72];

    const unsigned short* Qbase = Q + ((size_t)b * NC + h * NKD) * NHW;

    {
        int d = tid >> 3, nb_ = (tid & 7) * 16;
        const unsigned short* qp = Qbase + (size_t)d * NHW + n0 + nb_;
        u16x8 v0 = *reinterpret_cast<const u16x8*>(qp);
        u16x8 v1 = *reinterpret_cast<const u16x8*>(qp + 8);
        #pragma unroll
        for (int i = 0; i < 8; ++i) Qs[nb_ + i][d] = v0[i];
        #pragma unroll
        for (int i = 0; i < 8; ++i) Qs[nb_ + 8 + i][d] = v1[i];
    }
    if (tid < 128) {
        int d = tid >> 2, ag0 = (tid & 3) * 16;
        const float* ap = A_ + ((size_t)(b * NC + h * NKD + d)) * NAG + ag0;
        #pragma unroll
        for (int i = 0; i < 16; ++i) Ags[ag0 + i][d] = f2bf(ap[i] * FSCALE);
    }
    if (tid < 128) {
        int ag = tid >> 1, d0 = (tid & 1) * 16;
        const float* atp = AT + ((size_t)bh * NAG + ag) * NKD + d0;
        #pragma unroll
        for (int i = 0; i < 16; ++i) ATs[d0 + i][ag] = f2bf(atp[i]);
    }
    __syncthreads();

    f32x4 s[2][4];
    #pragma unroll
    for (int mi = 0; mi < 2; ++mi)
        #pragma unroll
        for (int ni = 0; ni < 4; ++ni)
            s[mi][ni] = (f32x4){0.f, 0.f, 0.f, 0.f};
    {
        bf16x8 qa[2], ab[4];
        #pragma unroll
        for (int mi = 0; mi < 2; ++mi)
            qa[mi] = *reinterpret_cast<const bf16x8*>(&Qs[wv * 32 + mi * 16 + lm][lg * 8]);
        #pragma unroll
        for (int ni = 0; ni < 4; ++ni)
            ab[ni] = *reinterpret_cast<const bf16x8*>(&Ags[ni * 16 + lm][lg * 8]);
        #pragma unroll
        for (int mi = 0; mi < 2; ++mi)
            #pragma unroll
            for (int ni = 0; ni < 4; ++ni)
                s[mi][ni] = __builtin_amdgcn_mfma_f32_16x16x32_bf16(qa[mi], ab[ni], s[mi][ni], 0, 0, 0);
    }

    float lsum[2][4];
    #pragma unroll
    for (int mi = 0; mi < 2; ++mi) {
        #pragma unroll
        for (int r = 0; r < 4; ++r) {
            float mx = fmaxf(fmaxf(s[mi][0][r], s[mi][1][r]), fmaxf(s[mi][2][r], s[mi][3][r]));
            mx = fmaxf(mx, __shfl_xor(mx, 1));
            mx = fmaxf(mx, __shfl_xor(mx, 2));
            mx = fmaxf(mx, __shfl_xor(mx, 4));
            mx = fmaxf(mx, __shfl_xor(mx, 8));
            int nrow = wv * 32 + mi * 16 + lg * 4 + r;
            float ls = 0.f;
            #pragma unroll
            for (int ni = 0; ni < 4; ++ni) {
                float p = __expf(s[mi][ni][r] - mx);
                ls += p;
                Ps[nrow][ni * 16 + lm] = f2bf(p);
            }
            ls += __shfl_xor(ls, 1);
            ls += __shfl_xor(ls, 2);
            ls += __shfl_xor(ls, 4);
            ls += __shfl_xor(ls, 8);
            lsum[mi][r] = ls;
        }
    }
    __syncthreads();

    f32x4 o[2][2];
    #pragma unroll
    for (int mi = 0; mi < 2; ++mi)
        #pragma unroll
        for (int ni = 0; ni < 2; ++ni)
            o[mi][ni] = (f32x4){0.f, 0.f, 0.f, 0.f};
    #pragma unroll
    for (int kk = 0; kk < 2; ++kk) {
        bf16x8 pa[2], vb[2];
        #pragma unroll
        for (int mi = 0; mi < 2; ++mi)
            pa[mi] = *reinterpret_cast<const bf16x8*>(&Ps[wv * 32 + mi * 16 + lm][kk * 32 + lg * 8]);
        #pragma unroll
        for (int ni = 0; ni < 2; ++ni)
            vb[ni] = *reinterpret_cast<const bf16x8*>(&ATs[ni * 16 + lm][kk * 32 + lg * 8]);
        #pragma unroll
        for (int mi = 0; mi < 2; ++mi)
            #pragma unroll
            for (int ni = 0; ni < 2; ++ni)
                o[mi][ni] = __builtin_amdgcn_mfma_f32_16x16x32_bf16(pa[mi], vb[ni], o[mi][ni], 0, 0, 0);
    }

    unsigned short* obase = O1t + ((size_t)b * NHW + n0) * NC + h * NKD;
    #pragma unroll
    for (int mi = 0; mi < 2; ++mi) {
        #pragma unroll
        for (int r = 0; r < 4; ++r) {
            float rl = 1.0f / lsum[mi][r];
            int n = wv * 32 + mi * 16 + lg * 4 + r;
            #pragma unroll
            for (int ni = 0; ni < 2; ++ni) {
                int d = ni * 16 + lm;
                obase[(size_t)n * NC + d] = f2bf(o[mi][ni][r] * rl);
            }
        }
    }
}

// ---------------- K6: O1t += BN(depthwise 3x3 conv of gated V) ----------------
__global__ __launch_bounds__(256) void k_pe(const unsigned short* __restrict__ V,
                                            const float* __restrict__ GV,
                                            const float* __restrict__ wpe,
                                            const float* __restrict__ bnp,
                                            unsigned short* __restrict__ O1t) {
    const int bh_ = blockIdx.x;
    const int b = bh_ >> 6, h = bh_ & 63;
    const int tid = threadIdx.x;
    __shared__ unsigned short vs[64 * 198];
    __shared__ float gvs[64][3];
    __shared__ float wps[64][9];
    __shared__ float bns[64][2];
    const int cl = tid & 63;
    const int wq = tid >> 6;

    for (int cc = 0; cc < 4; ++cc) {
        const int cbase = cc * 64;
        #pragma unroll
        for (int j = 0; j < 6; ++j) {
            int vecid = tid + 256 * j;
            int row = vecid >> 3, seg = vecid & 7;
            int c = row / 3, kh = row - c * 3;
            int hh = h + kh - 1;
            union { unsigned short u[8]; u16x8 w; } pk;
            if (hh >= 0 && hh < HDIM) {
                pk.w = *reinterpret_cast<const u16x8*>(
                    V + ((size_t)b * NC + cbase + c) * NHW + hh * WDIM + seg * 8);
            } else {
                #pragma unroll
                for (int i = 0; i < 8; ++i) pk.u[i] = 0;
            }
            *reinterpret_cast<u16x8*>(&vs[c * 198 + kh * 66 + 1 + seg * 8]) = pk.w;
        }
        if (tid < 192) {
            int c = tid / 3, kh = tid - c * 3;
            vs[c * 198 + kh * 66 + 0] = 0;
            vs[c * 198 + kh * 66 + 65] = 0;
            int hh = h + kh - 1;
            gvs[c][kh] = (hh >= 0 && hh < HDIM)
                ? GV[((size_t)b * NC + cbase + c) * HDIM + hh] : 0.f;
        }
        for (int i = tid; i < 64 * 9; i += 256)
            wps[i / 9][i % 9] = wpe[(cbase + i / 9) * 9 + i % 9];
        if (tid < 64) {
            int c = cbase + tid;
            float g = bnp[c], be = bnp[NC + c], m = bnp[2 * NC + c], vv = bnp[3 * NC + c];
            float inv = g * rsqrtf(vv + EPSF);
            bns[tid][0] = inv;
            bns[tid][1] = be - m * inv;
        }
        __syncthreads();

        float wr[9];
        #pragma unroll
        for (int i = 0; i < 9; ++i) wr[i] = wps[cl][i];
        float g0 = gvs[cl][0], g1 = gvs[cl][1], g2 = gvs[cl][2];
        float inv = bns[cl][0], bias = bns[cl][1];
        const unsigned short* vrow = &vs[cl * 198];
        unsigned short* obase = O1t + ((size_t)b * NHW + h * WDIM) * NC + cbase + cl;
        #pragma unroll
        for (int wi = 0; wi < 16; ++wi) {
            int w = wq * 16 + wi;
            float s0 = wr[0] * b2f(vrow[0 * 66 + w]) + wr[1] * b2f(vrow[0 * 66 + w + 1]) + wr[2] * b2f(vrow[0 * 66 + w + 2]);
            float s1 = wr[3] * b2f(vrow[1 * 66 + w]) + wr[4] * b2f(vrow[1 * 66 + w + 1]) + wr[5] * b2f(vrow[1 * 66 + w + 2]);
            float s2 = wr[6] * b2f(vrow[2 * 66 + w]) + wr[7] * b2f(vrow[2 * 66 + w + 1]) + wr[8] * b2f(vrow[2 * 66 + w + 2]);
            float s = s0 * g0 + s1 * g1 + s2 * g2;
            size_t oidx = (size_t)w * NC;
            obase[oidx] = f2bf(b2f(obase[oidx]) + s * inv + bias);
        }
        __syncthreads();
    }
}

// ---------------- K7: out = BN(wpb @ O1t), bf16 MFMA, gload_lds + coalesced epilogue ----------------
__global__ __launch_bounds__(256) void k_proj(const unsigned short* __restrict__ O1t,
                                              const unsigned short* __restrict__ wb,
                                              const float* __restrict__ bnp,
                                              float* __restrict__ out) {
    const int b   = blockIdx.z;
    const int ocB = blockIdx.y * 128;
    const int nB  = blockIdx.x * 128;
    const int tid = threadIdx.x;
    const int wv  = tid >> 6, lane = tid & 63;
    const int wm = wv >> 1, wn = wv & 1;
    const int lm = lane & 15, lg = lane >> 4;

    __shared__ __align__(16) unsigned short S[8192];   // As | Bs, reused as f32 epilogue buf
    unsigned short* As = S;
    unsigned short* Bs = S + 4096;
    __shared__ float inv_s[128], bias_s[128];

    if (tid < 128) {
        int oc = ocB + tid;
        float g = bnp[0 * NC + oc], be = bnp[1 * NC + oc];
        float m = bnp[2 * NC + oc], vv = bnp[3 * NC + oc];
        float inv = g * rsqrtf(vv + EPSF);
        inv_s[tid] = inv;
        bias_s[tid] = be - m * inv;
    }

    f32x4 acc[4][4];
    #pragma unroll
    for (int i = 0; i < 4; ++i)
        #pragma unroll
        for (int j = 0; j < 4; ++j)
            acc[i][j] = (f32x4){0.f, 0.f, 0.f, 0.f};

    const int srow = lane >> 2;
    const int kl = ((lane & 3) ^ ((lane >> 3) & 3)) * 8;
    const size_t agbase = (size_t)(ocB + wv * 32 + srow) * 256 + kl;
    const size_t bgbase = ((size_t)b * NHW + nB + wv * 32 + srow) * NC + kl;
    const int sw = (lm >> 1) & 3;

    for (int k0 = 0; k0 < 256; k0 += 32) {
        #pragma unroll
        for (int j = 0; j < 2; ++j) {
            gload_lds16(wb + agbase + (size_t)j * 16 * 256 + k0, &As[wv * 1024 + j * 512]);
            gload_lds16(O1t + bgbase + (size_t)j * 16 * NC + k0, &Bs[wv * 1024 + j * 512]);
        }
        __syncthreads();

        bf16x8 af[4], bfr[4];
        #pragma unroll
        for (int mi = 0; mi < 4; ++mi)
            af[mi] = *reinterpret_cast<const bf16x8*>(&As[(wm * 64 + mi * 16 + lm) * 32 + (lg ^ sw) * 8]);
        #pragma unroll
        for (int ni = 0; ni < 4; ++ni)
            bfr[ni] = *reinterpret_cast<const bf16x8*>(&Bs[(wn * 64 + ni * 16 + lm) * 32 + (lg ^ sw) * 8]);
        #pragma unroll
        for (int mi = 0; mi < 4; ++mi)
            #pragma unroll
            for (int ni = 0; ni < 4; ++ni)
                acc[mi][ni] = __builtin_amdgcn_mfma_f32_16x16x32_bf16(af[mi], bfr[ni], acc[mi][ni], 0, 0, 0);
        __syncthreads();
    }

    // epilogue: 4 chunks of 32 oc-rows through LDS (f32), coalesced float4 stores
    float* ts32 = (float*)S;
    for (int ch = 0; ch < 4; ++ch) {
        if (wm == (ch >> 1)) {
            #pragma unroll
            for (int mq = 0; mq < 2; ++mq) {
                int mi = (ch & 1) * 2 + mq;
                #pragma unroll
                for (int r = 0; r < 4; ++r) {
                    int rloc = mi * 16 + lg * 4 + r - (ch & 1) * 32;   // 0..31
                    int lo = ch * 32 + rloc;
                    float inv = inv_s[lo], bias = bias_s[lo];
                    #pragma unroll
                    for (int ni = 0; ni < 4; ++ni)
                        ts32[rloc * 128 + wn * 64 + ni * 16 + lm] = acc[mi][ni][r] * inv + bias;
                }
            }
        }
        __syncthreads();
        #pragma unroll
        for (int j = 0; j < 4; ++j) {
            int i = tid + 256 * j;
            int row = i >> 5, sg = i & 31;
            float4 v = *reinterpret_cast<const float4*>(&ts32[row * 128 + sg * 4]);
            *reinterpret_cast<float4*>(out + ((size_t)b * NC + ocB + ch * 32 + row) * NHW + nB + sg * 4) = v;
        }
        __syncthreads();
    }
}

extern "C" void kernel_launch(void* const* d_in, const int* in_sizes, int n_in,
                              void* d_out, int out_size, void* d_ws, size_t ws_size,
                              hipStream_t stream) {
    (void)in_sizes; (void)n_in; (void)out_size; (void)ws_size;
    const float* x       = (const float*)d_in[0];
    const float* w_qkv   = (const float*)d_in[1];
    const float* bn_qkv  = (const float*)d_in[2];
    const float* w_cv1   = (const float*)d_in[3];
    const float* bn_cv1  = (const float*)d_in[4];
    const float* w_cv2   = (const float*)d_in[5];
    const float* bn_cv2  = (const float*)d_in[6];
    const float* w_proj  = (const float*)d_in[7];
    const float* bn_proj = (const float*)d_in[8];
    const float* w_pe    = (const float*)d_in[9];
    const float* bn_pe   = (const float*)d_in[10];
    float* out = (float*)d_out;

    unsigned short* Qb  = (unsigned short*)d_ws;
    unsigned short* Kb  = Qb + SZQ;
    unsigned short* Vb  = Kb + SZQ;
    unsigned short* O1t = Vb + SZQ;
    unsigned short* xbt = O1t + SZQ;                    // SZQ bf16
    unsigned short* wqb = xbt + SZQ;                    // 196608
    unsigned short* wpb = wqb + 768 * 256;              // 65536
    float* Aa   = (float*)(wpb + 65536);
    float* AT   = Aa + (size_t)NB * NC * NAG;               // 131072
    float* Pm   = AT + (size_t)NB * NHEAD * NAG * NKD;      // 131072
    float* Pl   = Pm + (size_t)NB * NHEAD * NSPLIT * NAG;   // 65536
    float* Pacc = Pl + (size_t)NB * NHEAD * NSPLIT * NAG;   // 65536
    float* AMK  = Pacc + (size_t)NB * NHEAD * NSPLIT * NAG * NKD;  // 2.1M
    float* AMV  = AMK + (size_t)NB * HDIM * NC;             // 131072
    float* GK   = AMV + (size_t)NB * HDIM * NC;
    float* GV   = GK + (size_t)NB * NC * HDIM;

    k_xpose<<<dim3(64, NB), 256, 0, stream>>>(x, xbt);
    k_wcast<<<256, 256, 0, stream>>>(w_qkv, w_proj, wqb, wpb);
    k_qkv<<<dim3(32, 6, NB), 256, 0, stream>>>(xbt, wqb, bn_qkv, Qb, Kb, Vb);
    k_means<<<NB * NC, 256, 0, stream>>>(Kb, Vb, AMK, AMV);
    k_gatecomp<<<NB * HDIM, 256, 0, stream>>>(AMK, AMV, w_cv1, bn_cv1, w_cv2, bn_cv2, GK, GV);
    k_pool<<<NB * NC, 64, 0, stream>>>(Qb, Aa);
    k_attn_part<<<NB * NHEAD * NSPLIT, 256, 0, stream>>>(Kb, Vb, Aa, GK, GV, Pm, Pl, Pacc);
    k_attn_comb<<<NB * NHEAD, 256, 0, stream>>>(Pm, Pl, Pacc, AT);
    k_qattn<<<dim3(32, 64), 256, 0, stream>>>(Qb, Aa, AT, O1t);
    k_pe<<<NB * HDIM, 256, 0, stream>>>(Vb, GV, w_pe, bn_pe, O1t);
    k_proj<<<dim3(32, 2, NB), 256, 0, stream>>>(O1t, wpb, bn_proj, out);
}

// Round 13
// 148.535 us; speedup vs baseline: 1.0434x; 1.0434x over previous
//
#include <hip/hip_runtime.h>
#include <hip/hip_bf16.h>

#define NB 8
#define NC 256
#define NHW 4096       // H*W
#define HDIM 64
#define WDIM 64
#define NHEAD 8
#define NKD 32
#define NAG 64
#define NMIP 8
#define NSPLIT 16
#define EPSF 1e-5f
#define FSCALE 0.17677669529663687f  // 32^-0.5
#define SZQ ((size_t)NB * NC * NHW)

typedef __attribute__((ext_vector_type(8))) short bf16x8;
typedef __attribute__((ext_vector_type(8))) unsigned short u16x8;
typedef __attribute__((ext_vector_type(4))) unsigned short u16x4;
typedef __attribute__((ext_vector_type(4))) float f32x4;

__device__ __forceinline__ unsigned short f2bf(float f) {
    union { float f; unsigned u; } v; v.f = f;
    unsigned r = v.u + 0x7FFF + ((v.u >> 16) & 1);
    return (unsigned short)(r >> 16);
}
__device__ __forceinline__ float b2f(unsigned short u) {
    union { unsigned u32; float f; } v; v.u32 = ((unsigned)u) << 16; return v.f;
}
__device__ __forceinline__ void gload_lds16(const unsigned short* g, unsigned short* l) {
    __builtin_amdgcn_global_load_lds(
        (const __attribute__((address_space(1))) unsigned int*)g,
        (__attribute__((address_space(3))) unsigned int*)l, 16, 0, 0);
}

// ---------------- K0a: transpose+convert x -> xbt[b][n][c] bf16 ----------------
__global__ __launch_bounds__(256) void k_xpose(const float* __restrict__ x,
                                               unsigned short* __restrict__ xbt) {
    const int b = blockIdx.y;
    const int n0 = blockIdx.x * 64;
    const int tid = threadIdx.x;
    __shared__ unsigned short lt[64 * 258];   // [n][c], pad 2

    #pragma unroll
    for (int it = 0; it < 4; ++it) {
        int c = it * 64 + (tid >> 2);
        int nq = (tid & 3) * 16;
        const float* xp = x + ((size_t)b * NC + c) * NHW + n0 + nq;
        float4 v0 = reinterpret_cast<const float4*>(xp)[0];
        float4 v1 = reinterpret_cast<const float4*>(xp)[1];
        float4 v2 = reinterpret_cast<const float4*>(xp)[2];
        float4 v3 = reinterpret_cast<const float4*>(xp)[3];
        float t[16] = {v0.x,v0.y,v0.z,v0.w, v1.x,v1.y,v1.z,v1.w,
                       v2.x,v2.y,v2.z,v2.w, v3.x,v3.y,v3.z,v3.w};
        #pragma unroll
        for (int i = 0; i < 16; ++i)
            lt[(nq + i) * 258 + c] = f2bf(t[i]);
    }
    __syncthreads();

    const int n = tid >> 2, cq = tid & 3;
    unsigned short* dst = xbt + ((size_t)b * NHW + n0 + n) * NC + cq * 64;
    #pragma unroll
    for (int v = 0; v < 8; ++v) {
        union { unsigned short u[8]; u16x8 w; } pk;
        #pragma unroll
        for (int i = 0; i < 8; ++i)
            pk.u[i] = lt[n * 258 + cq * 64 + v * 8 + i];
        *reinterpret_cast<u16x8*>(dst + v * 8) = pk.w;
    }
}

// ---------------- K0b: pre-convert w_qkv and w_proj to bf16 ----------------
__global__ __launch_bounds__(256) void k_wcast(const float* __restrict__ wq,
                                               const float* __restrict__ wp,
                                               unsigned short* __restrict__ wqb,
                                               unsigned short* __restrict__ wpb) {
    const int i = (blockIdx.x * 256 + threadIdx.x) * 4;
    const int NQ = 768 * 256;
    if (i < NQ) {
        float4 v = *reinterpret_cast<const float4*>(wq + i);
        u16x4 u = {f2bf(v.x), f2bf(v.y), f2bf(v.z), f2bf(v.w)};
        *reinterpret_cast<u16x4*>(wqb + i) = u;
    } else {
        int j = i - NQ;
        float4 v = *reinterpret_cast<const float4*>(wp + j);
        u16x4 u = {f2bf(v.x), f2bf(v.y), f2bf(v.z), f2bf(v.w)};
        *reinterpret_cast<u16x4*>(wpb + j) = u;
    }
}

// ---------------- K1: qkv = BN(wb @ xbt), bf16 MFMA, gload_lds + wave-local epilogue ----------------
// grid (32, 6, 8); 256 thr = 4 waves (2x2), 128x128 tile, BK=32
__global__ __launch_bounds__(256) void k_qkv(const unsigned short* __restrict__ xbt,
                                             const unsigned short* __restrict__ wb,
                                             const float* __restrict__ bnp,
                                             unsigned short* __restrict__ Qb,
                                             unsigned short* __restrict__ Kb,
                                             unsigned short* __restrict__ Vb) {
    const int b   = blockIdx.z;
    const int ocB = blockIdx.y * 128;
    const int nB  = blockIdx.x * 128;
    const int tid = threadIdx.x;
    const int wv  = tid >> 6, lane = tid & 63;
    const int wm = wv >> 1, wn = wv & 1;
    const int lm = lane & 15, lg = lane >> 4;

    __shared__ unsigned short As[128 * 32];
    __shared__ unsigned short Bs[128 * 32];
    __shared__ unsigned short EP[4 * 16 * 72];   // wave-private epilogue staging

    f32x4 acc[4][4];
    #pragma unroll
    for (int i = 0; i < 4; ++i)
        #pragma unroll
        for (int j = 0; j < 4; ++j)
            acc[i][j] = (f32x4){0.f, 0.f, 0.f, 0.f};

    const int srow = lane >> 2;
    const int kl = ((lane & 3) ^ ((lane >> 3) & 3)) * 8;   // pre-swizzled source chunk
    const size_t agbase = (size_t)(ocB + wv * 32 + srow) * 256 + kl;
    const size_t bgbase = ((size_t)b * NHW + nB + wv * 32 + srow) * NC + kl;
    const int sw = (lm >> 1) & 3;                          // read-side XOR

    for (int k0 = 0; k0 < 256; k0 += 32) {
        #pragma unroll
        for (int j = 0; j < 2; ++j) {
            gload_lds16(wb + agbase + (size_t)j * 16 * 256 + k0, &As[wv * 1024 + j * 512]);
            gload_lds16(xbt + bgbase + (size_t)j * 16 * NC + k0, &Bs[wv * 1024 + j * 512]);
        }
        __syncthreads();

        bf16x8 af[4], bfr[4];
        #pragma unroll
        for (int mi = 0; mi < 4; ++mi)
            af[mi] = *reinterpret_cast<const bf16x8*>(&As[(wm * 64 + mi * 16 + lm) * 32 + (lg ^ sw) * 8]);
        #pragma unroll
        for (int ni = 0; ni < 4; ++ni)
            bfr[ni] = *reinterpret_cast<const bf16x8*>(&Bs[(wn * 64 + ni * 16 + lm) * 32 + (lg ^ sw) * 8]);
        #pragma unroll
        for (int mi = 0; mi < 4; ++mi)
            #pragma unroll
            for (int ni = 0; ni < 4; ++ni)
                acc[mi][ni] = __builtin_amdgcn_mfma_f32_16x16x32_bf16(af[mi], bfr[ni], acc[mi][ni], 0, 0, 0);
        __syncthreads();
    }

    // wave-local epilogue: per mi, stage 16 rows x 64 cols in wave-private LDS,
    // then store coalesced u16x8 rows. No __syncthreads needed (wave-local buffer).
    unsigned short* wep = EP + wv * (16 * 72);
    #pragma unroll
    for (int mi = 0; mi < 4; ++mi) {
        const int ocrow = ocB + wm * 64 + mi * 16;
        #pragma unroll
        for (int r = 0; r < 4; ++r) {
            int lo = lg * 4 + r;               // row within 16-row chunk
            int oc = ocrow + lo;
            float g = bnp[0 * 768 + oc], be = bnp[1 * 768 + oc];
            float m = bnp[2 * 768 + oc], vv = bnp[3 * 768 + oc];
            float inv = g * rsqrtf(vv + EPSF);
            float bias = be - m * inv;
            #pragma unroll
            for (int ni = 0; ni < 4; ++ni)
                wep[lo * 72 + ni * 16 + lm] = f2bf(acc[mi][ni][r] * inv + bias);
        }
        // read back + coalesced store (16 rows x 128B; 8 lanes per row)
        #pragma unroll
        for (int it = 0; it < 2; ++it) {
            int row = it * 8 + (lane >> 3);    // 0..15
            int seg = lane & 7;
            u16x8 v = *reinterpret_cast<const u16x8*>(&wep[row * 72 + seg * 8]);
            int oc = ocrow + row;
            unsigned short* base; int oc2;
            if (oc < 256)      { base = Qb; oc2 = oc; }
            else if (oc < 512) { base = Kb; oc2 = oc - 256; }
            else               { base = Vb; oc2 = oc - 512; }
            *reinterpret_cast<u16x8*>(base + ((size_t)b * NC + oc2) * NHW + nB + wn * 64 + seg * 8) = v;
        }
    }
}

// ---------------- K2a: per-(b,c,h) W-means of K and V ----------------
__global__ __launch_bounds__(256) void k_means(const unsigned short* __restrict__ K,
                                               const unsigned short* __restrict__ V,
                                               float* __restrict__ AMK,
                                               float* __restrict__ AMV) {
    const int bc = blockIdx.x;
    const int b = bc >> 8;
    const int c = bc & 255;
    const int t = threadIdx.x;
    #pragma unroll
    for (int pass = 0; pass < 2; ++pass) {
        const unsigned short* p = (pass ? V : K) + (size_t)bc * NHW + t * 16;
        u16x8 a0 = *reinterpret_cast<const u16x8*>(p);
        u16x8 a1 = *reinterpret_cast<const u16x8*>(p + 8);
        float s = 0.f;
        #pragma unroll
        for (int i = 0; i < 8; ++i) s += b2f(a0[i]);
        #pragma unroll
        for (int i = 0; i < 8; ++i) s += b2f(a1[i]);
        s += __shfl_xor(s, 1);
        s += __shfl_xor(s, 2);
        if ((t & 3) == 0)
            (pass ? AMV : AMK)[((size_t)b * HDIM + (t >> 2)) * NC + c] = s * (1.0f / 64.0f);
    }
}

// ---------------- K2b: SE gate values per (b,h) ----------------
__global__ __launch_bounds__(256) void k_gatecomp(const float* __restrict__ AMK,
                                                  const float* __restrict__ AMV,
                                                  const float* __restrict__ w1,
                                                  const float* __restrict__ bn1,
                                                  const float* __restrict__ w2,
                                                  const float* __restrict__ bn2,
                                                  float* __restrict__ GK,
                                                  float* __restrict__ GV) {
    const int b = blockIdx.x >> 6;
    const int h = blockIdx.x & 63;
    const int c = threadIdx.x;
    __shared__ float am[NC];
    __shared__ float m1[NMIP];
    for (int pass = 0; pass < 2; ++pass) {
        am[c] = (pass ? AMV : AMK)[((size_t)b * HDIM + h) * NC + c];
        __syncthreads();
        if (c < NMIP) {
            float t = 0.f;
            for (int cc = 0; cc < NC; ++cc) t += w1[c * NC + cc] * am[cc];
            float g = bn1[0 * NMIP + c], be = bn1[1 * NMIP + c];
            float mm = bn1[2 * NMIP + c], vv = bn1[3 * NMIP + c];
            float inv = g * rsqrtf(vv + EPSF);
            m1[c] = t * inv + (be - mm * inv);
        }
        __syncthreads();
        {
            float t = 0.f;
            #pragma unroll
            for (int j = 0; j < NMIP; ++j) t += w2[c * NMIP + j] * m1[j];
            float g = bn2[0 * NC + c], be = bn2[1 * NC + c];
            float mm = bn2[2 * NC + c], vv = bn2[3 * NC + c];
            float inv = g * rsqrtf(vv + EPSF);
            (pass ? GV : GK)[((size_t)b * NC + c) * HDIM + h] = t * inv + (be - mm * inv);
        }
        __syncthreads();
    }
}

// ---------------- K3: 8x8 block pool of Q -> agent tokens ----------------
__global__ __launch_bounds__(64) void k_pool(const unsigned short* __restrict__ Q,
                                             float* __restrict__ A_) {
    const int bc = blockIdx.x;
    const int ag = threadIdx.x;
    const int ph = ag >> 3, pw = ag & 7;
    const unsigned short* src = Q + (size_t)bc * NHW;
    float s = 0.f;
    #pragma unroll
    for (int i = 0; i < 8; ++i) {
        u16x8 v = *reinterpret_cast<const u16x8*>(&src[(ph * 8 + i) * WDIM + pw * 8]);
        #pragma unroll
        for (int j = 0; j < 8; ++j) s += b2f(v[j]);
    }
    A_[(size_t)bc * NAG + ag] = s * (1.0f / 64.0f);
}

// ---------------- K4a: agent attn partials (split-N flash), bf16 MFMA, gate-fused ----------------
__global__ __launch_bounds__(256) void k_attn_part(const unsigned short* __restrict__ K,
                                                   const unsigned short* __restrict__ V,
                                                   const float* __restrict__ A_,
                                                   const float* __restrict__ GK,
                                                   const float* __restrict__ GV,
                                                   float* __restrict__ Pm,
                                                   float* __restrict__ Pl,
                                                   float* __restrict__ Pacc) {
    const int bh = blockIdx.x >> 4;
    const int ns = blockIdx.x & (NSPLIT - 1);
    const int b = bh >> 3, h = bh & 7;
    const int tid = threadIdx.x;
    const int wv = tid >> 6, lane = tid & 63;
    const int lm = lane & 15, lg = lane >> 4;

    __shared__ unsigned short a_s[64 * 40];   // [ag][d]
    __shared__ unsigned short kt_s[64 * 40];  // [col][d]
    __shared__ unsigned short vt_s[32 * 72];  // [dd][col]
    __shared__ unsigned short Ps[64 * 72];    // [ag][col]

    {
        int d = tid >> 3, ag0 = (tid & 7) * 8;
        const float* ap = A_ + ((size_t)(b * NC + h * NKD + d)) * NAG + ag0;
        float4 v0 = reinterpret_cast<const float4*>(ap)[0];
        float4 v1 = reinterpret_cast<const float4*>(ap)[1];
        float t8[8] = {v0.x, v0.y, v0.z, v0.w, v1.x, v1.y, v1.z, v1.w};
        #pragma unroll
        for (int i = 0; i < 8; ++i)
            a_s[(ag0 + i) * 40 + d] = f2bf(t8[i] * FSCALE);
    }

    float mrow[4], lrow[4];
    f32x4 acc[2];
    #pragma unroll
    for (int r = 0; r < 4; ++r) { mrow[r] = -1e30f; lrow[r] = 0.f; }
    acc[0] = (f32x4){0.f, 0.f, 0.f, 0.f};
    acc[1] = (f32x4){0.f, 0.f, 0.f, 0.f};

    const int colbase = ns * (NHW / NSPLIT);
    const unsigned short* Kp = K + (size_t)(b * NC + h * NKD) * NHW + colbase;
    const unsigned short* Vp = V + (size_t)(b * NC + h * NKD) * NHW + colbase;
    const int sd = tid >> 3;
    const size_t gbase = ((size_t)(b * NC + h * NKD + sd)) * HDIM;
    __syncthreads();

    for (int nt = 0; nt < 4; ++nt) {
        const int gh = ns * 4 + nt;
        {
            int c0 = tid & 7;
            float gk = GK[gbase + gh];
            const unsigned short* kp = Kp + (size_t)sd * NHW + nt * 64 + c0;
            #pragma unroll
            for (int i = 0; i < 8; ++i)
                kt_s[(c0 + 8 * i) * 40 + sd] = f2bf(b2f(kp[8 * i]) * gk);
        }
        {
            int c0 = (tid & 7) * 8;
            float gv = GV[gbase + gh];
            const unsigned short* vp = Vp + (size_t)sd * NHW + nt * 64 + c0;
            u16x8 vr = *reinterpret_cast<const u16x8*>(vp);
            union { unsigned short u[8]; u16x8 v; } pk;
            #pragma unroll
            for (int i = 0; i < 8; ++i) pk.u[i] = f2bf(b2f(vr[i]) * gv);
            *reinterpret_cast<u16x8*>(&vt_s[sd * 72 + c0]) = pk.v;
        }
        __syncthreads();

        f32x4 s[4];
        {
            bf16x8 af = *reinterpret_cast<const bf16x8*>(&a_s[(wv * 16 + lm) * 40 + lg * 8]);
            #pragma unroll
            for (int ni = 0; ni < 4; ++ni) {
                bf16x8 kf = *reinterpret_cast<const bf16x8*>(&kt_s[(ni * 16 + lm) * 40 + lg * 8]);
                s[ni] = __builtin_amdgcn_mfma_f32_16x16x32_bf16(
                    af, kf, (f32x4){0.f, 0.f, 0.f, 0.f}, 0, 0, 0);
            }
        }

        float fsc[4];
        #pragma unroll
        for (int r = 0; r < 4; ++r) {
            float mx = fmaxf(fmaxf(s[0][r], s[1][r]), fmaxf(s[2][r], s[3][r]));
            mx = fmaxf(mx, __shfl_xor(mx, 1));
            mx = fmaxf(mx, __shfl_xor(mx, 2));
            mx = fmaxf(mx, __shfl_xor(mx, 4));
            mx = fmaxf(mx, __shfl_xor(mx, 8));
            float mnew = fmaxf(mrow[r], mx);
            fsc[r] = __expf(mrow[r] - mnew);
            mrow[r] = mnew;
            int agrow = wv * 16 + lg * 4 + r;
            float ps = 0.f;
            #pragma unroll
            for (int ni = 0; ni < 4; ++ni) {
                float p = __expf(s[ni][r] - mnew);
                Ps[agrow * 72 + ni * 16 + lm] = f2bf(p);
                ps += p;
            }
            ps += __shfl_xor(ps, 1);
            ps += __shfl_xor(ps, 2);
            ps += __shfl_xor(ps, 4);
            ps += __shfl_xor(ps, 8);
            lrow[r] = lrow[r] * fsc[r] + ps;
        }
        #pragma unroll
        for (int ni = 0; ni < 2; ++ni)
            #pragma unroll
            for (int r = 0; r < 4; ++r)
                acc[ni][r] *= fsc[r];
        __syncthreads();

        #pragma unroll
        for (int kk = 0; kk < 2; ++kk) {
            bf16x8 pa = *reinterpret_cast<const bf16x8*>(&Ps[(wv * 16 + lm) * 72 + kk * 32 + lg * 8]);
            #pragma unroll
            for (int ni = 0; ni < 2; ++ni) {
                bf16x8 vb = *reinterpret_cast<const bf16x8*>(&vt_s[(ni * 16 + lm) * 72 + kk * 32 + lg * 8]);
                acc[ni] = __builtin_amdgcn_mfma_f32_16x16x32_bf16(pa, vb, acc[ni], 0, 0, 0);
            }
        }
        __syncthreads();
    }

    const size_t pbase = (size_t)(bh * NSPLIT + ns) * NAG;
    #pragma unroll
    for (int r = 0; r < 4; ++r) {
        int ag = wv * 16 + lg * 4 + r;
        #pragma unroll
        for (int ni = 0; ni < 2; ++ni)
            Pacc[(pbase + ag) * NKD + ni * 16 + lm] = acc[ni][r];
        if (lm == 0) {
            Pm[pbase + ag] = mrow[r];
            Pl[pbase + ag] = lrow[r];
        }
    }
}

// ---------------- K4b: combine partials ----------------
__global__ __launch_bounds__(256) void k_attn_comb(const float* __restrict__ Pm,
                                                   const float* __restrict__ Pl,
                                                   const float* __restrict__ Pacc,
                                                   float* __restrict__ AT) {
    const int bh = blockIdx.x;
    const int tid = threadIdx.x;
    const int ag = tid >> 2, jg = tid & 3;
    float m = -1e30f;
    #pragma unroll
    for (int ns = 0; ns < NSPLIT; ++ns)
        m = fmaxf(m, Pm[(size_t)(bh * NSPLIT + ns) * NAG + ag]);
    float l = 0.f;
    float acc[8] = {};
    for (int ns = 0; ns < NSPLIT; ++ns) {
        size_t pb = (size_t)(bh * NSPLIT + ns) * NAG + ag;
        float f = __expf(Pm[pb] - m);
        l += Pl[pb] * f;
        const float* pp = Pacc + pb * NKD + jg * 8;
        #pragma unroll
        for (int i = 0; i < 8; ++i) acc[i] += pp[i] * f;
    }
    float linv = 1.0f / l;
    #pragma unroll
    for (int i = 0; i < 8; ++i)
        AT[((size_t)bh * NAG + ag) * NKD + jg * 8 + i] = acc[i] * linv;
}

// ---------------- K5: out1 = softmax_ag(q^T a) @ attn, bf16 MFMA, writes O1t[n][c] ----------------
__global__ __launch_bounds__(256) void k_qattn(const unsigned short* __restrict__ Q,
                                               const float* __restrict__ A_,
                                               const float* __restrict__ AT,
                                               unsigned short* __restrict__ O1t) {
    const int bh = blockIdx.y;
    const int b = bh >> 3, h = bh & 7;
    const int n0 = blockIdx.x * 128;
    const int tid = threadIdx.x;
    const int wv = tid >> 6, lane = tid & 63;
    const int lm = lane & 15, lg = lane >> 4;

    __shared__ unsigned short Qs[128][40];
    __shared__ unsigned short Ags[64][40];
    __shared__ unsigned short ATs[32][72];
    __shared__ unsigned short Ps[128][72];

    const unsigned short* Qbase = Q + ((size_t)b * NC + h * NKD) * NHW;

    {
        int d = tid >> 3, nb_ = (tid & 7) * 16;
        const unsigned short* qp = Qbase + (size_t)d * NHW + n0 + nb_;
        u16x8 v0 = *reinterpret_cast<const u16x8*>(qp);
        u16x8 v1 = *reinterpret_cast<const u16x8*>(qp + 8);
        #pragma unroll
        for (int i = 0; i < 8; ++i) Qs[nb_ + i][d] = v0[i];
        #pragma unroll
        for (int i = 0; i < 8; ++i) Qs[nb_ + 8 + i][d] = v1[i];
    }
    if (tid < 128) {
        int d = tid >> 2, ag0 = (tid & 3) * 16;
        const float* ap = A_ + ((size_t)(b * NC + h * NKD + d)) * NAG + ag0;
        #pragma unroll
        for (int i = 0; i < 16; ++i) Ags[ag0 + i][d] = f2bf(ap[i] * FSCALE);
    }
    if (tid < 128) {
        int ag = tid >> 1, d0 = (tid & 1) * 16;
        const float* atp = AT + ((size_t)bh * NAG + ag) * NKD + d0;
        #pragma unroll
        for (int i = 0; i < 16; ++i) ATs[d0 + i][ag] = f2bf(atp[i]);
    }
    __syncthreads();

    f32x4 s[2][4];
    #pragma unroll
    for (int mi = 0; mi < 2; ++mi)
        #pragma unroll
        for (int ni = 0; ni < 4; ++ni)
            s[mi][ni] = (f32x4){0.f, 0.f, 0.f, 0.f};
    {
        bf16x8 qa[2], ab[4];
        #pragma unroll
        for (int mi = 0; mi < 2; ++mi)
            qa[mi] = *reinterpret_cast<const bf16x8*>(&Qs[wv * 32 + mi * 16 + lm][lg * 8]);
        #pragma unroll
        for (int ni = 0; ni < 4; ++ni)
            ab[ni] = *reinterpret_cast<const bf16x8*>(&Ags[ni * 16 + lm][lg * 8]);
        #pragma unroll
        for (int mi = 0; mi < 2; ++mi)
            #pragma unroll
            for (int ni = 0; ni < 4; ++ni)
                s[mi][ni] = __builtin_amdgcn_mfma_f32_16x16x32_bf16(qa[mi], ab[ni], s[mi][ni], 0, 0, 0);
    }

    float lsum[2][4];
    #pragma unroll
    for (int mi = 0; mi < 2; ++mi) {
        #pragma unroll
        for (int r = 0; r < 4; ++r) {
            float mx = fmaxf(fmaxf(s[mi][0][r], s[mi][1][r]), fmaxf(s[mi][2][r], s[mi][3][r]));
            mx = fmaxf(mx, __shfl_xor(mx, 1));
            mx = fmaxf(mx, __shfl_xor(mx, 2));
            mx = fmaxf(mx, __shfl_xor(mx, 4));
            mx = fmaxf(mx, __shfl_xor(mx, 8));
            int nrow = wv * 32 + mi * 16 + lg * 4 + r;
            float ls = 0.f;
            #pragma unroll
            for (int ni = 0; ni < 4; ++ni) {
                float p = __expf(s[mi][ni][r] - mx);
                ls += p;
                Ps[nrow][ni * 16 + lm] = f2bf(p);
            }
            ls += __shfl_xor(ls, 1);
            ls += __shfl_xor(ls, 2);
            ls += __shfl_xor(ls, 4);
            ls += __shfl_xor(ls, 8);
            lsum[mi][r] = ls;
        }
    }
    __syncthreads();

    f32x4 o[2][2];
    #pragma unroll
    for (int mi = 0; mi < 2; ++mi)
        #pragma unroll
        for (int ni = 0; ni < 2; ++ni)
            o[mi][ni] = (f32x4){0.f, 0.f, 0.f, 0.f};
    #pragma unroll
    for (int kk = 0; kk < 2; ++kk) {
        bf16x8 pa[2], vb[2];
        #pragma unroll
        for (int mi = 0; mi < 2; ++mi)
            pa[mi] = *reinterpret_cast<const bf16x8*>(&Ps[wv * 32 + mi * 16 + lm][kk * 32 + lg * 8]);
        #pragma unroll
        for (int ni = 0; ni < 2; ++ni)
            vb[ni] = *reinterpret_cast<const bf16x8*>(&ATs[ni * 16 + lm][kk * 32 + lg * 8]);
        #pragma unroll
        for (int mi = 0; mi < 2; ++mi)
            #pragma unroll
            for (int ni = 0; ni < 2; ++ni)
                o[mi][ni] = __builtin_amdgcn_mfma_f32_16x16x32_bf16(pa[mi], vb[ni], o[mi][ni], 0, 0, 0);
    }

    unsigned short* obase = O1t + ((size_t)b * NHW + n0) * NC + h * NKD;
    #pragma unroll
    for (int mi = 0; mi < 2; ++mi) {
        #pragma unroll
        for (int r = 0; r < 4; ++r) {
            float rl = 1.0f / lsum[mi][r];
            int n = wv * 32 + mi * 16 + lg * 4 + r;
            #pragma unroll
            for (int ni = 0; ni < 2; ++ni) {
                int d = ni * 16 + lm;
                obase[(size_t)n * NC + d] = f2bf(o[mi][ni][r] * rl);
            }
        }
    }
}

// ---------------- K6: O1t += BN(depthwise 3x3 conv of gated V) ----------------
__global__ __launch_bounds__(256) void k_pe(const unsigned short* __restrict__ V,
                                            const float* __restrict__ GV,
                                            const float* __restrict__ wpe,
                                            const float* __restrict__ bnp,
                                            unsigned short* __restrict__ O1t) {
    const int bh_ = blockIdx.x;
    const int b = bh_ >> 6, h = bh_ & 63;
    const int tid = threadIdx.x;
    __shared__ unsigned short vs[64 * 198];
    __shared__ float gvs[64][3];
    __shared__ float wps[64][9];
    __shared__ float bns[64][2];
    const int cl = tid & 63;
    const int wq = tid >> 6;

    for (int cc = 0; cc < 4; ++cc) {
        const int cbase = cc * 64;
        #pragma unroll
        for (int j = 0; j < 6; ++j) {
            int vecid = tid + 256 * j;
            int row = vecid >> 3, seg = vecid & 7;
            int c = row / 3, kh = row - c * 3;
            int hh = h + kh - 1;
            union { unsigned short u[8]; u16x8 w; } pk;
            if (hh >= 0 && hh < HDIM) {
                pk.w = *reinterpret_cast<const u16x8*>(
                    V + ((size_t)b * NC + cbase + c) * NHW + hh * WDIM + seg * 8);
            } else {
                #pragma unroll
                for (int i = 0; i < 8; ++i) pk.u[i] = 0;
            }
            *reinterpret_cast<u16x8*>(&vs[c * 198 + kh * 66 + 1 + seg * 8]) = pk.w;
        }
        if (tid < 192) {
            int c = tid / 3, kh = tid - c * 3;
            vs[c * 198 + kh * 66 + 0] = 0;
            vs[c * 198 + kh * 66 + 65] = 0;
            int hh = h + kh - 1;
            gvs[c][kh] = (hh >= 0 && hh < HDIM)
                ? GV[((size_t)b * NC + cbase + c) * HDIM + hh] : 0.f;
        }
        for (int i = tid; i < 64 * 9; i += 256)
            wps[i / 9][i % 9] = wpe[(cbase + i / 9) * 9 + i % 9];
        if (tid < 64) {
            int c = cbase + tid;
            float g = bnp[c], be = bnp[NC + c], m = bnp[2 * NC + c], vv = bnp[3 * NC + c];
            float inv = g * rsqrtf(vv + EPSF);
            bns[tid][0] = inv;
            bns[tid][1] = be - m * inv;
        }
        __syncthreads();

        float wr[9];
        #pragma unroll
        for (int i = 0; i < 9; ++i) wr[i] = wps[cl][i];
        float g0 = gvs[cl][0], g1 = gvs[cl][1], g2 = gvs[cl][2];
        float inv = bns[cl][0], bias = bns[cl][1];
        const unsigned short* vrow = &vs[cl * 198];
        unsigned short* obase = O1t + ((size_t)b * NHW + h * WDIM) * NC + cbase + cl;
        #pragma unroll
        for (int wi = 0; wi < 16; ++wi) {
            int w = wq * 16 + wi;
            float s0 = wr[0] * b2f(vrow[0 * 66 + w]) + wr[1] * b2f(vrow[0 * 66 + w + 1]) + wr[2] * b2f(vrow[0 * 66 + w + 2]);
            float s1 = wr[3] * b2f(vrow[1 * 66 + w]) + wr[4] * b2f(vrow[1 * 66 + w + 1]) + wr[5] * b2f(vrow[1 * 66 + w + 2]);
            float s2 = wr[6] * b2f(vrow[2 * 66 + w]) + wr[7] * b2f(vrow[2 * 66 + w + 1]) + wr[8] * b2f(vrow[2 * 66 + w + 2]);
            float s = s0 * g0 + s1 * g1 + s2 * g2;
            size_t oidx = (size_t)w * NC;
            obase[oidx] = f2bf(b2f(obase[oidx]) + s * inv + bias);
        }
        __syncthreads();
    }
}

// ---------------- K7: out = BN(wpb @ O1t), bf16 MFMA, gload_lds staging ----------------
__global__ __launch_bounds__(256) void k_proj(const unsigned short* __restrict__ O1t,
                                              const unsigned short* __restrict__ wb,
                                              const float* __restrict__ bnp,
                                              float* __restrict__ out) {
    const int b   = blockIdx.z;
    const int ocB = blockIdx.y * 128;
    const int nB  = blockIdx.x * 128;
    const int tid = threadIdx.x;
    const int wv  = tid >> 6, lane = tid & 63;
    const int wm = wv >> 1, wn = wv & 1;
    const int lm = lane & 15, lg = lane >> 4;

    __shared__ unsigned short As[128 * 32];
    __shared__ unsigned short Bs[128 * 32];
    __shared__ float inv_s[128], bias_s[128];

    if (tid < 128) {
        int oc = ocB + tid;
        float g = bnp[0 * NC + oc], be = bnp[1 * NC + oc];
        float m = bnp[2 * NC + oc], vv = bnp[3 * NC + oc];
        float inv = g * rsqrtf(vv + EPSF);
        inv_s[tid] = inv;
        bias_s[tid] = be - m * inv;
    }

    f32x4 acc[4][4];
    #pragma unroll
    for (int i = 0; i < 4; ++i)
        #pragma unroll
        for (int j = 0; j < 4; ++j)
            acc[i][j] = (f32x4){0.f, 0.f, 0.f, 0.f};

    const int srow = lane >> 2;
    const int kl = ((lane & 3) ^ ((lane >> 3) & 3)) * 8;
    const size_t agbase = (size_t)(ocB + wv * 32 + srow) * 256 + kl;
    const size_t bgbase = ((size_t)b * NHW + nB + wv * 32 + srow) * NC + kl;
    const int sw = (lm >> 1) & 3;

    for (int k0 = 0; k0 < 256; k0 += 32) {
        #pragma unroll
        for (int j = 0; j < 2; ++j) {
            gload_lds16(wb + agbase + (size_t)j * 16 * 256 + k0, &As[wv * 1024 + j * 512]);
            gload_lds16(O1t + bgbase + (size_t)j * 16 * NC + k0, &Bs[wv * 1024 + j * 512]);
        }
        __syncthreads();

        bf16x8 af[4], bfr[4];
        #pragma unroll
        for (int mi = 0; mi < 4; ++mi)
            af[mi] = *reinterpret_cast<const bf16x8*>(&As[(wm * 64 + mi * 16 + lm) * 32 + (lg ^ sw) * 8]);
        #pragma unroll
        for (int ni = 0; ni < 4; ++ni)
            bfr[ni] = *reinterpret_cast<const bf16x8*>(&Bs[(wn * 64 + ni * 16 + lm) * 32 + (lg ^ sw) * 8]);
        #pragma unroll
        for (int mi = 0; mi < 4; ++mi)
            #pragma unroll
            for (int ni = 0; ni < 4; ++ni)
                acc[mi][ni] = __builtin_amdgcn_mfma_f32_16x16x32_bf16(af[mi], bfr[ni], acc[mi][ni], 0, 0, 0);
        __syncthreads();
    }

    float* dstb = out + ((size_t)b * NC + ocB) * NHW + nB;
    #pragma unroll
    for (int mi = 0; mi < 4; ++mi) {
        int lo_base = wm * 64 + mi * 16 + lg * 4;
        #pragma unroll
        for (int r = 0; r < 4; ++r) {
            int lo = lo_base + r;
            float inv = inv_s[lo], bias = bias_s[lo];
            #pragma unroll
            for (int ni = 0; ni < 4; ++ni) {
                int n = wn * 64 + ni * 16 + lm;
                dstb[(size_t)lo * NHW + n] = acc[mi][ni][r] * inv + bias;
            }
        }
    }
}

extern "C" void kernel_launch(void* const* d_in, const int* in_sizes, int n_in,
                              void* d_out, int out_size, void* d_ws, size_t ws_size,
                              hipStream_t stream) {
    (void)in_sizes; (void)n_in; (void)out_size; (void)ws_size;
    const float* x       = (const float*)d_in[0];
    const float* w_qkv   = (const float*)d_in[1];
    const float* bn_qkv  = (const float*)d_in[2];
    const float* w_cv1   = (const float*)d_in[3];
    const float* bn_cv1  = (const float*)d_in[4];
    const float* w_cv2   = (const float*)d_in[5];
    const float* bn_cv2  = (const float*)d_in[6];
    const float* w_proj  = (const float*)d_in[7];
    const float* bn_proj = (const float*)d_in[8];
    const float* w_pe    = (const float*)d_in[9];
    const float* bn_pe   = (const float*)d_in[10];
    float* out = (float*)d_out;

    unsigned short* Qb  = (unsigned short*)d_ws;
    unsigned short* Kb  = Qb + SZQ;
    unsigned short* Vb  = Kb + SZQ;
    unsigned short* O1t = Vb + SZQ;
    unsigned short* xbt = O1t + SZQ;                    // SZQ bf16
    unsigned short* wqb = xbt + SZQ;                    // 196608
    unsigned short* wpb = wqb + 768 * 256;              // 65536
    float* Aa   = (float*)(wpb + 65536);
    float* AT   = Aa + (size_t)NB * NC * NAG;               // 131072
    float* Pm   = AT + (size_t)NB * NHEAD * NAG * NKD;      // 131072
    float* Pl   = Pm + (size_t)NB * NHEAD * NSPLIT * NAG;   // 65536
    float* Pacc = Pl + (size_t)NB * NHEAD * NSPLIT * NAG;   // 65536
    float* AMK  = Pacc + (size_t)NB * NHEAD * NSPLIT * NAG * NKD;  // 2.1M
    float* AMV  = AMK + (size_t)NB * HDIM * NC;             // 131072
    float* GK   = AMV + (size_t)NB * HDIM * NC;
    float* GV   = GK + (size_t)NB * NC * HDIM;

    k_xpose<<<dim3(64, NB), 256, 0, stream>>>(x, xbt);
    k_wcast<<<256, 256, 0, stream>>>(w_qkv, w_proj, wqb, wpb);
    k_qkv<<<dim3(32, 6, NB), 256, 0, stream>>>(xbt, wqb, bn_qkv, Qb, Kb, Vb);
    k_means<<<NB * NC, 256, 0, stream>>>(Kb, Vb, AMK, AMV);
    k_gatecomp<<<NB * HDIM, 256, 0, stream>>>(AMK, AMV, w_cv1, bn_cv1, w_cv2, bn_cv2, GK, GV);
    k_pool<<<NB * NC, 64, 0, stream>>>(Qb, Aa);
    k_attn_part<<<NB * NHEAD * NSPLIT, 256, 0, stream>>>(Kb, Vb, Aa, GK, GV, Pm, Pl, Pacc);
    k_attn_comb<<<NB * NHEAD, 256, 0, stream>>>(Pm, Pl, Pacc, AT);
    k_qattn<<<dim3(32, 64), 256, 0, stream>>>(Qb, Aa, AT, O1t);
    k_pe<<<NB * HDIM, 256, 0, stream>>>(Vb, GV, w_pe, bn_pe, O1t);
    k_proj<<<dim3(32, 2, NB), 256, 0, stream>>>(O1t, wpb, bn_proj, out);
}

// Round 14
// 143.781 us; speedup vs baseline: 1.0780x; 1.0331x over previous
//
#include <hip/hip_runtime.h>
#include <hip/hip_bf16.h>

#define NB 8
#define NC 256
#define NHW 4096       // H*W
#define HDIM 64
#define WDIM 64
#define NHEAD 8
#define NKD 32
#define NAG 64
#define NMIP 8
#define NSPLIT 16
#define EPSF 1e-5f
#define FSCALE 0.17677669529663687f  // 32^-0.5
#define SZQ ((size_t)NB * NC * NHW)

typedef __attribute__((ext_vector_type(8))) short bf16x8;
typedef __attribute__((ext_vector_type(8))) unsigned short u16x8;
typedef __attribute__((ext_vector_type(4))) unsigned short u16x4;
typedef __attribute__((ext_vector_type(4))) float f32x4;

__device__ __forceinline__ unsigned short f2bf(float f) {
    union { float f; unsigned u; } v; v.f = f;
    unsigned r = v.u + 0x7FFF + ((v.u >> 16) & 1);
    return (unsigned short)(r >> 16);
}
__device__ __forceinline__ float b2f(unsigned short u) {
    union { unsigned u32; float f; } v; v.u32 = ((unsigned)u) << 16; return v.f;
}
__device__ __forceinline__ void gload_lds16(const unsigned short* g, unsigned short* l) {
    __builtin_amdgcn_global_load_lds(
        (const __attribute__((address_space(1))) unsigned int*)g,
        (__attribute__((address_space(3))) unsigned int*)l, 16, 0, 0);
}

// ---------------- K0a: transpose+convert x -> xbt[b][n][c] bf16 ----------------
__global__ __launch_bounds__(256) void k_xpose(const float* __restrict__ x,
                                               unsigned short* __restrict__ xbt) {
    const int b = blockIdx.y;
    const int n0 = blockIdx.x * 64;
    const int tid = threadIdx.x;
    __shared__ unsigned short lt[64 * 258];   // [n][c], pad 2

    #pragma unroll
    for (int it = 0; it < 4; ++it) {
        int c = it * 64 + (tid >> 2);
        int nq = (tid & 3) * 16;
        const float* xp = x + ((size_t)b * NC + c) * NHW + n0 + nq;
        float4 v0 = reinterpret_cast<const float4*>(xp)[0];
        float4 v1 = reinterpret_cast<const float4*>(xp)[1];
        float4 v2 = reinterpret_cast<const float4*>(xp)[2];
        float4 v3 = reinterpret_cast<const float4*>(xp)[3];
        float t[16] = {v0.x,v0.y,v0.z,v0.w, v1.x,v1.y,v1.z,v1.w,
                       v2.x,v2.y,v2.z,v2.w, v3.x,v3.y,v3.z,v3.w};
        #pragma unroll
        for (int i = 0; i < 16; ++i)
            lt[(nq + i) * 258 + c] = f2bf(t[i]);
    }
    __syncthreads();

    const int n = tid >> 2, cq = tid & 3;
    unsigned short* dst = xbt + ((size_t)b * NHW + n0 + n) * NC + cq * 64;
    #pragma unroll
    for (int v = 0; v < 8; ++v) {
        union { unsigned short u[8]; u16x8 w; } pk;
        #pragma unroll
        for (int i = 0; i < 8; ++i)
            pk.u[i] = lt[n * 258 + cq * 64 + v * 8 + i];
        *reinterpret_cast<u16x8*>(dst + v * 8) = pk.w;
    }
}

// ---------------- K0b: pre-convert w_qkv and w_proj to bf16 ----------------
__global__ __launch_bounds__(256) void k_wcast(const float* __restrict__ wq,
                                               const float* __restrict__ wp,
                                               unsigned short* __restrict__ wqb,
                                               unsigned short* __restrict__ wpb) {
    const int i = (blockIdx.x * 256 + threadIdx.x) * 4;
    const int NQ = 768 * 256;
    if (i < NQ) {
        float4 v = *reinterpret_cast<const float4*>(wq + i);
        u16x4 u = {f2bf(v.x), f2bf(v.y), f2bf(v.z), f2bf(v.w)};
        *reinterpret_cast<u16x4*>(wqb + i) = u;
    } else {
        int j = i - NQ;
        float4 v = *reinterpret_cast<const float4*>(wp + j);
        u16x4 u = {f2bf(v.x), f2bf(v.y), f2bf(v.z), f2bf(v.w)};
        *reinterpret_cast<u16x4*>(wpb + j) = u;
    }
}

// ---------------- K1: qkv = BN(wb @ xbt), bf16 MFMA, gload_lds; fused W-means ----------------
// grid (32, 6, 8); 256 thr = 4 waves (2x2), 128x128 tile, BK=32
__global__ __launch_bounds__(256) void k_qkv(const unsigned short* __restrict__ xbt,
                                             const unsigned short* __restrict__ wb,
                                             const float* __restrict__ bnp,
                                             unsigned short* __restrict__ Qb,
                                             unsigned short* __restrict__ Kb,
                                             unsigned short* __restrict__ Vb,
                                             float* __restrict__ AMK,
                                             float* __restrict__ AMV) {
    const int b   = blockIdx.z;
    const int ocB = blockIdx.y * 128;
    const int nB  = blockIdx.x * 128;
    const int tid = threadIdx.x;
    const int wv  = tid >> 6, lane = tid & 63;
    const int wm = wv >> 1, wn = wv & 1;
    const int lm = lane & 15, lg = lane >> 4;

    __shared__ unsigned short As[128 * 32];
    __shared__ unsigned short Bs[128 * 32];
    __shared__ unsigned short EP[4 * 16 * 72];   // wave-private epilogue staging

    f32x4 acc[4][4];
    #pragma unroll
    for (int i = 0; i < 4; ++i)
        #pragma unroll
        for (int j = 0; j < 4; ++j)
            acc[i][j] = (f32x4){0.f, 0.f, 0.f, 0.f};

    const int srow = lane >> 2;
    const int kl = ((lane & 3) ^ ((lane >> 3) & 3)) * 8;   // pre-swizzled source chunk
    const size_t agbase = (size_t)(ocB + wv * 32 + srow) * 256 + kl;
    const size_t bgbase = ((size_t)b * NHW + nB + wv * 32 + srow) * NC + kl;
    const int sw = (lm >> 1) & 3;                          // read-side XOR

    for (int k0 = 0; k0 < 256; k0 += 32) {
        #pragma unroll
        for (int j = 0; j < 2; ++j) {
            gload_lds16(wb + agbase + (size_t)j * 16 * 256 + k0, &As[wv * 1024 + j * 512]);
            gload_lds16(xbt + bgbase + (size_t)j * 16 * NC + k0, &Bs[wv * 1024 + j * 512]);
        }
        __syncthreads();

        bf16x8 af[4], bfr[4];
        #pragma unroll
        for (int mi = 0; mi < 4; ++mi)
            af[mi] = *reinterpret_cast<const bf16x8*>(&As[(wm * 64 + mi * 16 + lm) * 32 + (lg ^ sw) * 8]);
        #pragma unroll
        for (int ni = 0; ni < 4; ++ni)
            bfr[ni] = *reinterpret_cast<const bf16x8*>(&Bs[(wn * 64 + ni * 16 + lm) * 32 + (lg ^ sw) * 8]);
        #pragma unroll
        for (int mi = 0; mi < 4; ++mi)
            #pragma unroll
            for (int ni = 0; ni < 4; ++ni)
                acc[mi][ni] = __builtin_amdgcn_mfma_f32_16x16x32_bf16(af[mi], bfr[ni], acc[mi][ni], 0, 0, 0);
        __syncthreads();
    }

    // wave-local epilogue (no barriers): stage 16x64 in wave-private LDS, store
    // coalesced u16x8 rows; fused per-(c,h) W-mean for K/V panels (wave's 64
    // cols == one full spatial row h = nB/64 + wn).
    const int h_sp = (nB >> 6) + wn;
    unsigned short* wep = EP + wv * (16 * 72);
    #pragma unroll
    for (int mi = 0; mi < 4; ++mi) {
        const int ocrow = ocB + wm * 64 + mi * 16;
        #pragma unroll
        for (int r = 0; r < 4; ++r) {
            int lo = lg * 4 + r;
            int oc = ocrow + lo;
            float g = bnp[0 * 768 + oc], be = bnp[1 * 768 + oc];
            float m = bnp[2 * 768 + oc], vv = bnp[3 * 768 + oc];
            float inv = g * rsqrtf(vv + EPSF);
            float bias = be - m * inv;
            #pragma unroll
            for (int ni = 0; ni < 4; ++ni)
                wep[lo * 72 + ni * 16 + lm] = f2bf(acc[mi][ni][r] * inv + bias);
        }
        #pragma unroll
        for (int it = 0; it < 2; ++it) {
            int row = it * 8 + (lane >> 3);    // 0..15
            int seg = lane & 7;
            u16x8 v = *reinterpret_cast<const u16x8*>(&wep[row * 72 + seg * 8]);
            int oc = ocrow + row;
            unsigned short* base; int oc2;
            if (oc < 256)      { base = Qb; oc2 = oc; }
            else if (oc < 512) { base = Kb; oc2 = oc - 256; }
            else               { base = Vb; oc2 = oc - 512; }
            *reinterpret_cast<u16x8*>(base + ((size_t)b * NC + oc2) * NHW + nB + wn * 64 + seg * 8) = v;
            if (ocrow >= 256) {            // K or V panel: fused W-mean
                float s = 0.f;
                #pragma unroll
                for (int j = 0; j < 8; ++j) s += b2f(v[j]);
                s += __shfl_xor(s, 1);
                s += __shfl_xor(s, 2);
                s += __shfl_xor(s, 4);
                if (seg == 0) {
                    float* am = (oc < 512) ? AMK : AMV;
                    am[((size_t)b * HDIM + h_sp) * NC + oc2] = s * (1.0f / 64.0f);
                }
            }
        }
    }
}

// ---------------- K2b: SE gate values per (b,h) ----------------
__global__ __launch_bounds__(256) void k_gatecomp(const float* __restrict__ AMK,
                                                  const float* __restrict__ AMV,
                                                  const float* __restrict__ w1,
                                                  const float* __restrict__ bn1,
                                                  const float* __restrict__ w2,
                                                  const float* __restrict__ bn2,
                                                  float* __restrict__ GK,
                                                  float* __restrict__ GV) {
    const int b = blockIdx.x >> 6;
    const int h = blockIdx.x & 63;
    const int c = threadIdx.x;
    __shared__ float am[NC];
    __shared__ float m1[NMIP];
    for (int pass = 0; pass < 2; ++pass) {
        am[c] = (pass ? AMV : AMK)[((size_t)b * HDIM + h) * NC + c];
        __syncthreads();
        if (c < NMIP) {
            float t = 0.f;
            for (int cc = 0; cc < NC; ++cc) t += w1[c * NC + cc] * am[cc];
            float g = bn1[0 * NMIP + c], be = bn1[1 * NMIP + c];
            float mm = bn1[2 * NMIP + c], vv = bn1[3 * NMIP + c];
            float inv = g * rsqrtf(vv + EPSF);
            m1[c] = t * inv + (be - mm * inv);
        }
        __syncthreads();
        {
            float t = 0.f;
            #pragma unroll
            for (int j = 0; j < NMIP; ++j) t += w2[c * NMIP + j] * m1[j];
            float g = bn2[0 * NC + c], be = bn2[1 * NC + c];
            float mm = bn2[2 * NC + c], vv = bn2[3 * NC + c];
            float inv = g * rsqrtf(vv + EPSF);
            (pass ? GV : GK)[((size_t)b * NC + c) * HDIM + h] = t * inv + (be - mm * inv);
        }
        __syncthreads();
    }
}

// ---------------- K3: 8x8 block pool of Q -> agent tokens ----------------
__global__ __launch_bounds__(64) void k_pool(const unsigned short* __restrict__ Q,
                                             float* __restrict__ A_) {
    const int bc = blockIdx.x;
    const int ag = threadIdx.x;
    const int ph = ag >> 3, pw = ag & 7;
    const unsigned short* src = Q + (size_t)bc * NHW;
    float s = 0.f;
    #pragma unroll
    for (int i = 0; i < 8; ++i) {
        u16x8 v = *reinterpret_cast<const u16x8*>(&src[(ph * 8 + i) * WDIM + pw * 8]);
        #pragma unroll
        for (int j = 0; j < 8; ++j) s += b2f(v[j]);
    }
    A_[(size_t)bc * NAG + ag] = s * (1.0f / 64.0f);
}

// ---------------- K4a: agent attn partials (split-N flash), bf16 MFMA, gate-fused ----------------
__global__ __launch_bounds__(256) void k_attn_part(const unsigned short* __restrict__ K,
                                                   const unsigned short* __restrict__ V,
                                                   const float* __restrict__ A_,
                                                   const float* __restrict__ GK,
                                                   const float* __restrict__ GV,
                                                   float* __restrict__ Pm,
                                                   float* __restrict__ Pl,
                                                   float* __restrict__ Pacc) {
    const int bh = blockIdx.x >> 4;
    const int ns = blockIdx.x & (NSPLIT - 1);
    const int b = bh >> 3, h = bh & 7;
    const int tid = threadIdx.x;
    const int wv = tid >> 6, lane = tid & 63;
    const int lm = lane & 15, lg = lane >> 4;

    __shared__ unsigned short a_s[64 * 40];   // [ag][d]
    __shared__ unsigned short kt_s[64 * 40];  // [col][d]
    __shared__ unsigned short vt_s[32 * 72];  // [dd][col]
    __shared__ unsigned short Ps[64 * 72];    // [ag][col]

    {
        int d = tid >> 3, ag0 = (tid & 7) * 8;
        const float* ap = A_ + ((size_t)(b * NC + h * NKD + d)) * NAG + ag0;
        float4 v0 = reinterpret_cast<const float4*>(ap)[0];
        float4 v1 = reinterpret_cast<const float4*>(ap)[1];
        float t8[8] = {v0.x, v0.y, v0.z, v0.w, v1.x, v1.y, v1.z, v1.w};
        #pragma unroll
        for (int i = 0; i < 8; ++i)
            a_s[(ag0 + i) * 40 + d] = f2bf(t8[i] * FSCALE);
    }

    float mrow[4], lrow[4];
    f32x4 acc[2];
    #pragma unroll
    for (int r = 0; r < 4; ++r) { mrow[r] = -1e30f; lrow[r] = 0.f; }
    acc[0] = (f32x4){0.f, 0.f, 0.f, 0.f};
    acc[1] = (f32x4){0.f, 0.f, 0.f, 0.f};

    const int colbase = ns * (NHW / NSPLIT);
    const unsigned short* Kp = K + (size_t)(b * NC + h * NKD) * NHW + colbase;
    const unsigned short* Vp = V + (size_t)(b * NC + h * NKD) * NHW + colbase;
    const int sd = tid >> 3;
    const size_t gbase = ((size_t)(b * NC + h * NKD + sd)) * HDIM;
    __syncthreads();

    for (int nt = 0; nt < 4; ++nt) {
        const int gh = ns * 4 + nt;
        {
            int c0 = tid & 7;
            float gk = GK[gbase + gh];
            const unsigned short* kp = Kp + (size_t)sd * NHW + nt * 64 + c0;
            #pragma unroll
            for (int i = 0; i < 8; ++i)
                kt_s[(c0 + 8 * i) * 40 + sd] = f2bf(b2f(kp[8 * i]) * gk);
        }
        {
            int c0 = (tid & 7) * 8;
            float gv = GV[gbase + gh];
            const unsigned short* vp = Vp + (size_t)sd * NHW + nt * 64 + c0;
            u16x8 vr = *reinterpret_cast<const u16x8*>(vp);
            union { unsigned short u[8]; u16x8 v; } pk;
            #pragma unroll
            for (int i = 0; i < 8; ++i) pk.u[i] = f2bf(b2f(vr[i]) * gv);
            *reinterpret_cast<u16x8*>(&vt_s[sd * 72 + c0]) = pk.v;
        }
        __syncthreads();

        f32x4 s[4];
        {
            bf16x8 af = *reinterpret_cast<const bf16x8*>(&a_s[(wv * 16 + lm) * 40 + lg * 8]);
            #pragma unroll
            for (int ni = 0; ni < 4; ++ni) {
                bf16x8 kf = *reinterpret_cast<const bf16x8*>(&kt_s[(ni * 16 + lm) * 40 + lg * 8]);
                s[ni] = __builtin_amdgcn_mfma_f32_16x16x32_bf16(
                    af, kf, (f32x4){0.f, 0.f, 0.f, 0.f}, 0, 0, 0);
            }
        }

        float fsc[4];
        #pragma unroll
        for (int r = 0; r < 4; ++r) {
            float mx = fmaxf(fmaxf(s[0][r], s[1][r]), fmaxf(s[2][r], s[3][r]));
            mx = fmaxf(mx, __shfl_xor(mx, 1));
            mx = fmaxf(mx, __shfl_xor(mx, 2));
            mx = fmaxf(mx, __shfl_xor(mx, 4));
            mx = fmaxf(mx, __shfl_xor(mx, 8));
            float mnew = fmaxf(mrow[r], mx);
            fsc[r] = __expf(mrow[r] - mnew);
            mrow[r] = mnew;
            int agrow = wv * 16 + lg * 4 + r;
            float ps = 0.f;
            #pragma unroll
            for (int ni = 0; ni < 4; ++ni) {
                float p = __expf(s[ni][r] - mnew);
                Ps[agrow * 72 + ni * 16 + lm] = f2bf(p);
                ps += p;
            }
            ps += __shfl_xor(ps, 1);
            ps += __shfl_xor(ps, 2);
            ps += __shfl_xor(ps, 4);
            ps += __shfl_xor(ps, 8);
            lrow[r] = lrow[r] * fsc[r] + ps;
        }
        #pragma unroll
        for (int ni = 0; ni < 2; ++ni)
            #pragma unroll
            for (int r = 0; r < 4; ++r)
                acc[ni][r] *= fsc[r];
        __syncthreads();

        #pragma unroll
        for (int kk = 0; kk < 2; ++kk) {
            bf16x8 pa = *reinterpret_cast<const bf16x8*>(&Ps[(wv * 16 + lm) * 72 + kk * 32 + lg * 8]);
            #pragma unroll
            for (int ni = 0; ni < 2; ++ni) {
                bf16x8 vb = *reinterpret_cast<const bf16x8*>(&vt_s[(ni * 16 + lm) * 72 + kk * 32 + lg * 8]);
                acc[ni] = __builtin_amdgcn_mfma_f32_16x16x32_bf16(pa, vb, acc[ni], 0, 0, 0);
            }
        }
        __syncthreads();
    }

    const size_t pbase = (size_t)(bh * NSPLIT + ns) * NAG;
    #pragma unroll
    for (int r = 0; r < 4; ++r) {
        int ag = wv * 16 + lg * 4 + r;
        #pragma unroll
        for (int ni = 0; ni < 2; ++ni)
            Pacc[(pbase + ag) * NKD + ni * 16 + lm] = acc[ni][r];
        if (lm == 0) {
            Pm[pbase + ag] = mrow[r];
            Pl[pbase + ag] = lrow[r];
        }
    }
}

// ---------------- K4b: combine partials ----------------
__global__ __launch_bounds__(256) void k_attn_comb(const float* __restrict__ Pm,
                                                   const float* __restrict__ Pl,
                                                   const float* __restrict__ Pacc,
                                                   float* __restrict__ AT) {
    const int bh = blockIdx.x;
    const int tid = threadIdx.x;
    const int ag = tid >> 2, jg = tid & 3;
    float m = -1e30f;
    #pragma unroll
    for (int ns = 0; ns < NSPLIT; ++ns)
        m = fmaxf(m, Pm[(size_t)(bh * NSPLIT + ns) * NAG + ag]);
    float l = 0.f;
    float acc[8] = {};
    for (int ns = 0; ns < NSPLIT; ++ns) {
        size_t pb = (size_t)(bh * NSPLIT + ns) * NAG + ag;
        float f = __expf(Pm[pb] - m);
        l += Pl[pb] * f;
        const float* pp = Pacc + pb * NKD + jg * 8;
        #pragma unroll
        for (int i = 0; i < 8; ++i) acc[i] += pp[i] * f;
    }
    float linv = 1.0f / l;
    #pragma unroll
    for (int i = 0; i < 8; ++i)
        AT[((size_t)bh * NAG + ag) * NKD + jg * 8 + i] = acc[i] * linv;
}

// ---------------- K5: out1 = softmax_ag(q^T a) @ attn, bf16 MFMA, writes O1t[n][c] ----------------
__global__ __launch_bounds__(256) void k_qattn(const unsigned short* __restrict__ Q,
                                               const float* __restrict__ A_,
                                               const float* __restrict__ AT,
                                               unsigned short* __restrict__ O1t) {
    const int bh = blockIdx.y;
    const int b = bh >> 3, h = bh & 7;
    const int n0 = blockIdx.x * 128;
    const int tid = threadIdx.x;
    const int wv = tid >> 6, lane = tid & 63;
    const int lm = lane & 15, lg = lane >> 4;

    __shared__ unsigned short Qs[128][40];
    __shared__ unsigned short Ags[64][40];
    __shared__ unsigned short ATs[32][72];
    __shared__ unsigned short Ps[128][72];

    const unsigned short* Qbase = Q + ((size_t)b * NC + h * NKD) * NHW;

    {
        int d = tid >> 3, nb_ = (tid & 7) * 16;
        const unsigned short* qp = Qbase + (size_t)d * NHW + n0 + nb_;
        u16x8 v0 = *reinterpret_cast<const u16x8*>(qp);
        u16x8 v1 = *reinterpret_cast<const u16x8*>(qp + 8);
        #pragma unroll
        for (int i = 0; i < 8; ++i) Qs[nb_ + i][d] = v0[i];
        #pragma unroll
        for (int i = 0; i < 8; ++i) Qs[nb_ + 8 + i][d] = v1[i];
    }
    if (tid < 128) {
        int d = tid >> 2, ag0 = (tid & 3) * 16;
        const float* ap = A_ + ((size_t)(b * NC + h * NKD + d)) * NAG + ag0;
        #pragma unroll
        for (int i = 0; i < 16; ++i) Ags[ag0 + i][d] = f2bf(ap[i] * FSCALE);
    }
    if (tid < 128) {
        int ag = tid >> 1, d0 = (tid & 1) * 16;
        const float* atp = AT + ((size_t)bh * NAG + ag) * NKD + d0;
        #pragma unroll
        for (int i = 0; i < 16; ++i) ATs[d0 + i][ag] = f2bf(atp[i]);
    }
    __syncthreads();

    f32x4 s[2][4];
    #pragma unroll
    for (int mi = 0; mi < 2; ++mi)
        #pragma unroll
        for (int ni = 0; ni < 4; ++ni)
            s[mi][ni] = (f32x4){0.f, 0.f, 0.f, 0.f};
    {
        bf16x8 qa[2], ab[4];
        #pragma unroll
        for (int mi = 0; mi < 2; ++mi)
            qa[mi] = *reinterpret_cast<const bf16x8*>(&Qs[wv * 32 + mi * 16 + lm][lg * 8]);
        #pragma unroll
        for (int ni = 0; ni < 4; ++ni)
            ab[ni] = *reinterpret_cast<const bf16x8*>(&Ags[ni * 16 + lm][lg * 8]);
        #pragma unroll
        for (int mi = 0; mi < 2; ++mi)
            #pragma unroll
            for (int ni = 0; ni < 4; ++ni)
                s[mi][ni] = __builtin_amdgcn_mfma_f32_16x16x32_bf16(qa[mi], ab[ni], s[mi][ni], 0, 0, 0);
    }

    float lsum[2][4];
    #pragma unroll
    for (int mi = 0; mi < 2; ++mi) {
        #pragma unroll
        for (int r = 0; r < 4; ++r) {
            float mx = fmaxf(fmaxf(s[mi][0][r], s[mi][1][r]), fmaxf(s[mi][2][r], s[mi][3][r]));
            mx = fmaxf(mx, __shfl_xor(mx, 1));
            mx = fmaxf(mx, __shfl_xor(mx, 2));
            mx = fmaxf(mx, __shfl_xor(mx, 4));
            mx = fmaxf(mx, __shfl_xor(mx, 8));
            int nrow = wv * 32 + mi * 16 + lg * 4 + r;
            float ls = 0.f;
            #pragma unroll
            for (int ni = 0; ni < 4; ++ni) {
                float p = __expf(s[mi][ni][r] - mx);
                ls += p;
                Ps[nrow][ni * 16 + lm] = f2bf(p);
            }
            ls += __shfl_xor(ls, 1);
            ls += __shfl_xor(ls, 2);
            ls += __shfl_xor(ls, 4);
            ls += __shfl_xor(ls, 8);
            lsum[mi][r] = ls;
        }
    }
    __syncthreads();

    f32x4 o[2][2];
    #pragma unroll
    for (int mi = 0; mi < 2; ++mi)
        #pragma unroll
        for (int ni = 0; ni < 2; ++ni)
            o[mi][ni] = (f32x4){0.f, 0.f, 0.f, 0.f};
    #pragma unroll
    for (int kk = 0; kk < 2; ++kk) {
        bf16x8 pa[2], vb[2];
        #pragma unroll
        for (int mi = 0; mi < 2; ++mi)
            pa[mi] = *reinterpret_cast<const bf16x8*>(&Ps[wv * 32 + mi * 16 + lm][kk * 32 + lg * 8]);
        #pragma unroll
        for (int ni = 0; ni < 2; ++ni)
            vb[ni] = *reinterpret_cast<const bf16x8*>(&ATs[ni * 16 + lm][kk * 32 + lg * 8]);
        #pragma unroll
        for (int mi = 0; mi < 2; ++mi)
            #pragma unroll
            for (int ni = 0; ni < 2; ++ni)
                o[mi][ni] = __builtin_amdgcn_mfma_f32_16x16x32_bf16(pa[mi], vb[ni], o[mi][ni], 0, 0, 0);
    }

    unsigned short* obase = O1t + ((size_t)b * NHW + n0) * NC + h * NKD;
    #pragma unroll
    for (int mi = 0; mi < 2; ++mi) {
        #pragma unroll
        for (int r = 0; r < 4; ++r) {
            float rl = 1.0f / lsum[mi][r];
            int n = wv * 32 + mi * 16 + lg * 4 + r;
            #pragma unroll
            for (int ni = 0; ni < 2; ++ni) {
                int d = ni * 16 + lm;
                obase[(size_t)n * NC + d] = f2bf(o[mi][ni][r] * rl);
            }
        }
    }
}

// ---------------- K6: O1t += BN(depthwise 3x3 conv of gated V) ----------------
__global__ __launch_bounds__(256) void k_pe(const unsigned short* __restrict__ V,
                                            const float* __restrict__ GV,
                                            const float* __restrict__ wpe,
                                            const float* __restrict__ bnp,
                                            unsigned short* __restrict__ O1t) {
    const int bh_ = blockIdx.x;
    const int b = bh_ >> 6, h = bh_ & 63;
    const int tid = threadIdx.x;
    __shared__ unsigned short vs[64 * 198];
    __shared__ float gvs[64][3];
    __shared__ float wps[64][9];
    __shared__ float bns[64][2];
    const int cl = tid & 63;
    const int wq = tid >> 6;

    for (int cc = 0; cc < 4; ++cc) {
        const int cbase = cc * 64;
        #pragma unroll
        for (int j = 0; j < 6; ++j) {
            int vecid = tid + 256 * j;
            int row = vecid >> 3, seg = vecid & 7;
            int c = row / 3, kh = row - c * 3;
            int hh = h + kh - 1;
            union { unsigned short u[8]; u16x8 w; } pk;
            if (hh >= 0 && hh < HDIM) {
                pk.w = *reinterpret_cast<const u16x8*>(
                    V + ((size_t)b * NC + cbase + c) * NHW + hh * WDIM + seg * 8);
            } else {
                #pragma unroll
                for (int i = 0; i < 8; ++i) pk.u[i] = 0;
            }
            *reinterpret_cast<u16x8*>(&vs[c * 198 + kh * 66 + 1 + seg * 8]) = pk.w;
        }
        if (tid < 192) {
            int c = tid / 3, kh = tid - c * 3;
            vs[c * 198 + kh * 66 + 0] = 0;
            vs[c * 198 + kh * 66 + 65] = 0;
            int hh = h + kh - 1;
            gvs[c][kh] = (hh >= 0 && hh < HDIM)
                ? GV[((size_t)b * NC + cbase + c) * HDIM + hh] : 0.f;
        }
        for (int i = tid; i < 64 * 9; i += 256)
            wps[i / 9][i % 9] = wpe[(cbase + i / 9) * 9 + i % 9];
        if (tid < 64) {
            int c = cbase + tid;
            float g = bnp[c], be = bnp[NC + c], m = bnp[2 * NC + c], vv = bnp[3 * NC + c];
            float inv = g * rsqrtf(vv + EPSF);
            bns[tid][0] = inv;
            bns[tid][1] = be - m * inv;
        }
        __syncthreads();

        float wr[9];
        #pragma unroll
        for (int i = 0; i < 9; ++i) wr[i] = wps[cl][i];
        float g0 = gvs[cl][0], g1 = gvs[cl][1], g2 = gvs[cl][2];
        float inv = bns[cl][0], bias = bns[cl][1];
        const unsigned short* vrow = &vs[cl * 198];
        unsigned short* obase = O1t + ((size_t)b * NHW + h * WDIM) * NC + cbase + cl;
        #pragma unroll
        for (int wi = 0; wi < 16; ++wi) {
            int w = wq * 16 + wi;
            float s0 = wr[0] * b2f(vrow[0 * 66 + w]) + wr[1] * b2f(vrow[0 * 66 + w + 1]) + wr[2] * b2f(vrow[0 * 66 + w + 2]);
            float s1 = wr[3] * b2f(vrow[1 * 66 + w]) + wr[4] * b2f(vrow[1 * 66 + w + 1]) + wr[5] * b2f(vrow[1 * 66 + w + 2]);
            float s2 = wr[6] * b2f(vrow[2 * 66 + w]) + wr[7] * b2f(vrow[2 * 66 + w + 1]) + wr[8] * b2f(vrow[2 * 66 + w + 2]);
            float s = s0 * g0 + s1 * g1 + s2 * g2;
            size_t oidx = (size_t)w * NC;
            obase[oidx] = f2bf(b2f(obase[oidx]) + s * inv + bias);
        }
        __syncthreads();
    }
}

// ---------------- K7: out = BN(wpb @ O1t), bf16 MFMA, gload_lds staging ----------------
__global__ __launch_bounds__(256) void k_proj(const unsigned short* __restrict__ O1t,
                                              const unsigned short* __restrict__ wb,
                                              const float* __restrict__ bnp,
                                              float* __restrict__ out) {
    const int b   = blockIdx.z;
    const int ocB = blockIdx.y * 128;
    const int nB  = blockIdx.x * 128;
    const int tid = threadIdx.x;
    const int wv  = tid >> 6, lane = tid & 63;
    const int wm = wv >> 1, wn = wv & 1;
    const int lm = lane & 15, lg = lane >> 4;

    __shared__ unsigned short As[128 * 32];
    __shared__ unsigned short Bs[128 * 32];
    __shared__ float inv_s[128], bias_s[128];

    if (tid < 128) {
        int oc = ocB + tid;
        float g = bnp[0 * NC + oc], be = bnp[1 * NC + oc];
        float m = bnp[2 * NC + oc], vv = bnp[3 * NC + oc];
        float inv = g * rsqrtf(vv + EPSF);
        inv_s[tid] = inv;
        bias_s[tid] = be - m * inv;
    }

    f32x4 acc[4][4];
    #pragma unroll
    for (int i = 0; i < 4; ++i)
        #pragma unroll
        for (int j = 0; j < 4; ++j)
            acc[i][j] = (f32x4){0.f, 0.f, 0.f, 0.f};

    const int srow = lane >> 2;
    const int kl = ((lane & 3) ^ ((lane >> 3) & 3)) * 8;
    const size_t agbase = (size_t)(ocB + wv * 32 + srow) * 256 + kl;
    const size_t bgbase = ((size_t)b * NHW + nB + wv * 32 + srow) * NC + kl;
    const int sw = (lm >> 1) & 3;

    for (int k0 = 0; k0 < 256; k0 += 32) {
        #pragma unroll
        for (int j = 0; j < 2; ++j) {
            gload_lds16(wb + agbase + (size_t)j * 16 * 256 + k0, &As[wv * 1024 + j * 512]);
            gload_lds16(O1t + bgbase + (size_t)j * 16 * NC + k0, &Bs[wv * 1024 + j * 512]);
        }
        __syncthreads();

        bf16x8 af[4], bfr[4];
        #pragma unroll
        for (int mi = 0; mi < 4; ++mi)
            af[mi] = *reinterpret_cast<const bf16x8*>(&As[(wm * 64 + mi * 16 + lm) * 32 + (lg ^ sw) * 8]);
        #pragma unroll
        for (int ni = 0; ni < 4; ++ni)
            bfr[ni] = *reinterpret_cast<const bf16x8*>(&Bs[(wn * 64 + ni * 16 + lm) * 32 + (lg ^ sw) * 8]);
        #pragma unroll
        for (int mi = 0; mi < 4; ++mi)
            #pragma unroll
            for (int ni = 0; ni < 4; ++ni)
                acc[mi][ni] = __builtin_amdgcn_mfma_f32_16x16x32_bf16(af[mi], bfr[ni], acc[mi][ni], 0, 0, 0);
        __syncthreads();
    }

    float* dstb = out + ((size_t)b * NC + ocB) * NHW + nB;
    #pragma unroll
    for (int mi = 0; mi < 4; ++mi) {
        int lo_base = wm * 64 + mi * 16 + lg * 4;
        #pragma unroll
        for (int r = 0; r < 4; ++r) {
            int lo = lo_base + r;
            float inv = inv_s[lo], bias = bias_s[lo];
            #pragma unroll
            for (int ni = 0; ni < 4; ++ni) {
                int n = wn * 64 + ni * 16 + lm;
                dstb[(size_t)lo * NHW + n] = acc[mi][ni][r] * inv + bias;
            }
        }
    }
}

extern "C" void kernel_launch(void* const* d_in, const int* in_sizes, int n_in,
                              void* d_out, int out_size, void* d_ws, size_t ws_size,
                              hipStream_t stream) {
    (void)in_sizes; (void)n_in; (void)out_size; (void)ws_size;
    const float* x       = (const float*)d_in[0];
    const float* w_qkv   = (const float*)d_in[1];
    const float* bn_qkv  = (const float*)d_in[2];
    const float* w_cv1   = (const float*)d_in[3];
    const float* bn_cv1  = (const float*)d_in[4];
    const float* w_cv2   = (const float*)d_in[5];
    const float* bn_cv2  = (const float*)d_in[6];
    const float* w_proj  = (const float*)d_in[7];
    const float* bn_proj = (const float*)d_in[8];
    const float* w_pe    = (const float*)d_in[9];
    const float* bn_pe   = (const float*)d_in[10];
    float* out = (float*)d_out;

    unsigned short* Qb  = (unsigned short*)d_ws;
    unsigned short* Kb  = Qb + SZQ;
    unsigned short* Vb  = Kb + SZQ;
    unsigned short* O1t = Vb + SZQ;
    unsigned short* xbt = O1t + SZQ;                    // SZQ bf16
    unsigned short* wqb = xbt + SZQ;                    // 196608
    unsigned short* wpb = wqb + 768 * 256;              // 65536
    float* Aa   = (float*)(wpb + 65536);
    float* AT   = Aa + (size_t)NB * NC * NAG;               // 131072
    float* Pm   = AT + (size_t)NB * NHEAD * NAG * NKD;      // 131072
    float* Pl   = Pm + (size_t)NB * NHEAD * NSPLIT * NAG;   // 65536
    float* Pacc = Pl + (size_t)NB * NHEAD * NSPLIT * NAG;   // 65536
    float* AMK  = Pacc + (size_t)NB * NHEAD * NSPLIT * NAG * NKD;  // 2.1M
    float* AMV  = AMK + (size_t)NB * HDIM * NC;             // 131072
    float* GK   = AMV + (size_t)NB * HDIM * NC;
    float* GV   = GK + (size_t)NB * NC * HDIM;

    k_xpose<<<dim3(64, NB), 256, 0, stream>>>(x, xbt);
    k_wcast<<<256, 256, 0, stream>>>(w_qkv, w_proj, wqb, wpb);
    k_qkv<<<dim3(32, 6, NB), 256, 0, stream>>>(xbt, wqb, bn_qkv, Qb, Kb, Vb, AMK, AMV);
    k_gatecomp<<<NB * HDIM, 256, 0, stream>>>(AMK, AMV, w_cv1, bn_cv1, w_cv2, bn_cv2, GK, GV);
    k_pool<<<NB * NC, 64, 0, stream>>>(Qb, Aa);
    k_attn_part<<<NB * NHEAD * NSPLIT, 256, 0, stream>>>(Kb, Vb, Aa, GK, GV, Pm, Pl, Pacc);
    k_attn_comb<<<NB * NHEAD, 256, 0, stream>>>(Pm, Pl, Pacc, AT);
    k_qattn<<<dim3(32, 64), 256, 0, stream>>>(Qb, Aa, AT, O1t);
    k_pe<<<NB * HDIM, 256, 0, stream>>>(Vb, GV, w_pe, bn_pe, O1t);
    k_proj<<<dim3(32, 2, NB), 256, 0, stream>>>(O1t, wpb, bn_proj, out);
}

// Round 15
// 142.791 us; speedup vs baseline: 1.0854x; 1.0069x over previous
//
#include <hip/hip_runtime.h>
#include <hip/hip_bf16.h>

#define NB 8
#define NC 256
#define NHW 4096       // H*W
#define HDIM 64
#define WDIM 64
#define NHEAD 8
#define NKD 32
#define NAG 64
#define NMIP 8
#define NSPLIT 16
#define EPSF 1e-5f
#define FSCALE 0.17677669529663687f  // 32^-0.5
#define SZQ ((size_t)NB * NC * NHW)

typedef __attribute__((ext_vector_type(8))) short bf16x8;
typedef __attribute__((ext_vector_type(8))) unsigned short u16x8;
typedef __attribute__((ext_vector_type(4))) unsigned short u16x4;
typedef __attribute__((ext_vector_type(4))) float f32x4;

__device__ __forceinline__ unsigned short f2bf(float f) {
    union { float f; unsigned u; } v; v.f = f;
    unsigned r = v.u + 0x7FFF + ((v.u >> 16) & 1);
    return (unsigned short)(r >> 16);
}
__device__ __forceinline__ float b2f(unsigned short u) {
    union { unsigned u32; float f; } v; v.u32 = ((unsigned)u) << 16; return v.f;
}
__device__ __forceinline__ void gload_lds16(const unsigned short* g, unsigned short* l) {
    __builtin_amdgcn_global_load_lds(
        (const __attribute__((address_space(1))) unsigned int*)g,
        (__attribute__((address_space(3))) unsigned int*)l, 16, 0, 0);
}

// ---------------- K0a: transpose+convert x -> xbt[b][n][c] bf16 ----------------
__global__ __launch_bounds__(256) void k_xpose(const float* __restrict__ x,
                                               unsigned short* __restrict__ xbt) {
    const int b = blockIdx.y;
    const int n0 = blockIdx.x * 64;
    const int tid = threadIdx.x;
    __shared__ unsigned short lt[64 * 258];   // [n][c], pad 2

    #pragma unroll
    for (int it = 0; it < 4; ++it) {
        int c = it * 64 + (tid >> 2);
        int nq = (tid & 3) * 16;
        const float* xp = x + ((size_t)b * NC + c) * NHW + n0 + nq;
        float4 v0 = reinterpret_cast<const float4*>(xp)[0];
        float4 v1 = reinterpret_cast<const float4*>(xp)[1];
        float4 v2 = reinterpret_cast<const float4*>(xp)[2];
        float4 v3 = reinterpret_cast<const float4*>(xp)[3];
        float t[16] = {v0.x,v0.y,v0.z,v0.w, v1.x,v1.y,v1.z,v1.w,
                       v2.x,v2.y,v2.z,v2.w, v3.x,v3.y,v3.z,v3.w};
        #pragma unroll
        for (int i = 0; i < 16; ++i)
            lt[(nq + i) * 258 + c] = f2bf(t[i]);
    }
    __syncthreads();

    const int n = tid >> 2, cq = tid & 3;
    unsigned short* dst = xbt + ((size_t)b * NHW + n0 + n) * NC + cq * 64;
    #pragma unroll
    for (int v = 0; v < 8; ++v) {
        union { unsigned short u[8]; u16x8 w; } pk;
        #pragma unroll
        for (int i = 0; i < 8; ++i)
            pk.u[i] = lt[n * 258 + cq * 64 + v * 8 + i];
        *reinterpret_cast<u16x8*>(dst + v * 8) = pk.w;
    }
}

// ---------------- K0b: pre-convert w_qkv and w_proj to bf16 ----------------
__global__ __launch_bounds__(256) void k_wcast(const float* __restrict__ wq,
                                               const float* __restrict__ wp,
                                               unsigned short* __restrict__ wqb,
                                               unsigned short* __restrict__ wpb) {
    const int i = (blockIdx.x * 256 + threadIdx.x) * 4;
    const int NQ = 768 * 256;
    if (i < NQ) {
        float4 v = *reinterpret_cast<const float4*>(wq + i);
        u16x4 u = {f2bf(v.x), f2bf(v.y), f2bf(v.z), f2bf(v.w)};
        *reinterpret_cast<u16x4*>(wqb + i) = u;
    } else {
        int j = i - NQ;
        float4 v = *reinterpret_cast<const float4*>(wp + j);
        u16x4 u = {f2bf(v.x), f2bf(v.y), f2bf(v.z), f2bf(v.w)};
        *reinterpret_cast<u16x4*>(wpb + j) = u;
    }
}

// ---------------- K1: qkv = BN(wb @ xbt), bf16 MFMA, 2-phase pipelined gload_lds ----------------
// grid (32, 6, 8); 256 thr = 4 waves (2x2), 128x128 tile, BK=32, double-buffered
__global__ __launch_bounds__(256) void k_qkv(const unsigned short* __restrict__ xbt,
                                             const unsigned short* __restrict__ wb,
                                             const float* __restrict__ bnp,
                                             unsigned short* __restrict__ Qb,
                                             unsigned short* __restrict__ Kb,
                                             unsigned short* __restrict__ Vb,
                                             float* __restrict__ AMK,
                                             float* __restrict__ AMV) {
    const int b   = blockIdx.z;
    const int ocB = blockIdx.y * 128;
    const int nB  = blockIdx.x * 128;
    const int tid = threadIdx.x;
    const int wv  = tid >> 6, lane = tid & 63;
    const int wm = wv >> 1, wn = wv & 1;
    const int lm = lane & 15, lg = lane >> 4;

    __shared__ __align__(16) unsigned short S[2][8192];   // [buf]{As:4096 | Bs:4096}

    f32x4 acc[4][4];
    #pragma unroll
    for (int i = 0; i < 4; ++i)
        #pragma unroll
        for (int j = 0; j < 4; ++j)
            acc[i][j] = (f32x4){0.f, 0.f, 0.f, 0.f};

    const int srow = lane >> 2;
    const int kl = ((lane & 3) ^ ((lane >> 3) & 3)) * 8;   // pre-swizzled source chunk
    const size_t agbase = (size_t)(ocB + wv * 32 + srow) * 256 + kl;
    const size_t bgbase = ((size_t)b * NHW + nB + wv * 32 + srow) * NC + kl;
    const int sw = (lm >> 1) & 3;                          // read-side XOR

    auto STAGE = [&](int buf, int k0) {
        #pragma unroll
        for (int j = 0; j < 2; ++j) {
            gload_lds16(wb + agbase + (size_t)j * 16 * 256 + k0, &S[buf][wv * 1024 + j * 512]);
            gload_lds16(xbt + bgbase + (size_t)j * 16 * NC + k0, &S[buf][4096 + wv * 1024 + j * 512]);
        }
    };

    STAGE(0, 0);
    asm volatile("s_waitcnt vmcnt(0)" ::: "memory");
    __builtin_amdgcn_s_barrier();
    __builtin_amdgcn_sched_barrier(0);

    int cur = 0;
    for (int t = 0; t < 8; ++t) {
        if (t < 7) STAGE(cur ^ 1, (t + 1) * 32);

        const unsigned short* As = &S[cur][0];
        const unsigned short* Bs = &S[cur][4096];
        bf16x8 af[4], bfr[4];
        #pragma unroll
        for (int mi = 0; mi < 4; ++mi)
            af[mi] = *reinterpret_cast<const bf16x8*>(&As[(wm * 64 + mi * 16 + lm) * 32 + (lg ^ sw) * 8]);
        #pragma unroll
        for (int ni = 0; ni < 4; ++ni)
            bfr[ni] = *reinterpret_cast<const bf16x8*>(&Bs[(wn * 64 + ni * 16 + lm) * 32 + (lg ^ sw) * 8]);
        #pragma unroll
        for (int mi = 0; mi < 4; ++mi)
            #pragma unroll
            for (int ni = 0; ni < 4; ++ni)
                acc[mi][ni] = __builtin_amdgcn_mfma_f32_16x16x32_bf16(af[mi], bfr[ni], acc[mi][ni], 0, 0, 0);

        if (t < 7) {
            asm volatile("s_waitcnt vmcnt(0)" ::: "memory");
            __builtin_amdgcn_s_barrier();
            __builtin_amdgcn_sched_barrier(0);
            cur ^= 1;
        }
    }
    // t=7 computed from S[1]; S[0] is dead for all waves -> wave-private EP aliases it.

    const int h_sp = (nB >> 6) + wn;
    unsigned short* wep = &S[0][0] + wv * 1152;            // 16*72 u16 per wave
    #pragma unroll
    for (int mi = 0; mi < 4; ++mi) {
        const int ocrow = ocB + wm * 64 + mi * 16;
        #pragma unroll
        for (int r = 0; r < 4; ++r) {
            int lo = lg * 4 + r;
            int oc = ocrow + lo;
            float g = bnp[0 * 768 + oc], be = bnp[1 * 768 + oc];
            float m = bnp[2 * 768 + oc], vv = bnp[3 * 768 + oc];
            float inv = g * rsqrtf(vv + EPSF);
            float bias = be - m * inv;
            #pragma unroll
            for (int ni = 0; ni < 4; ++ni)
                wep[lo * 72 + ni * 16 + lm] = f2bf(acc[mi][ni][r] * inv + bias);
        }
        #pragma unroll
        for (int it = 0; it < 2; ++it) {
            int row = it * 8 + (lane >> 3);    // 0..15
            int seg = lane & 7;
            u16x8 v = *reinterpret_cast<const u16x8*>(&wep[row * 72 + seg * 8]);
            int oc = ocrow + row;
            unsigned short* base; int oc2;
            if (oc < 256)      { base = Qb; oc2 = oc; }
            else if (oc < 512) { base = Kb; oc2 = oc - 256; }
            else               { base = Vb; oc2 = oc - 512; }
            *reinterpret_cast<u16x8*>(base + ((size_t)b * NC + oc2) * NHW + nB + wn * 64 + seg * 8) = v;
            if (ocrow >= 256) {            // K or V panel: fused W-mean
                float s = 0.f;
                #pragma unroll
                for (int j = 0; j < 8; ++j) s += b2f(v[j]);
                s += __shfl_xor(s, 1);
                s += __shfl_xor(s, 2);
                s += __shfl_xor(s, 4);
                if (seg == 0) {
                    float* am = (oc < 512) ? AMK : AMV;
                    am[((size_t)b * HDIM + h_sp) * NC + oc2] = s * (1.0f / 64.0f);
                }
            }
        }
    }
}

// ---------------- K2b: SE gate values per (b,h) ----------------
__global__ __launch_bounds__(256) void k_gatecomp(const float* __restrict__ AMK,
                                                  const float* __restrict__ AMV,
                                                  const float* __restrict__ w1,
                                                  const float* __restrict__ bn1,
                                                  const float* __restrict__ w2,
                                                  const float* __restrict__ bn2,
                                                  float* __restrict__ GK,
                                                  float* __restrict__ GV) {
    const int b = blockIdx.x >> 6;
    const int h = blockIdx.x & 63;
    const int c = threadIdx.x;
    __shared__ float am[NC];
    __shared__ float m1[NMIP];
    for (int pass = 0; pass < 2; ++pass) {
        am[c] = (pass ? AMV : AMK)[((size_t)b * HDIM + h) * NC + c];
        __syncthreads();
        if (c < NMIP) {
            float t = 0.f;
            for (int cc = 0; cc < NC; ++cc) t += w1[c * NC + cc] * am[cc];
            float g = bn1[0 * NMIP + c], be = bn1[1 * NMIP + c];
            float mm = bn1[2 * NMIP + c], vv = bn1[3 * NMIP + c];
            float inv = g * rsqrtf(vv + EPSF);
            m1[c] = t * inv + (be - mm * inv);
        }
        __syncthreads();
        {
            float t = 0.f;
            #pragma unroll
            for (int j = 0; j < NMIP; ++j) t += w2[c * NMIP + j] * m1[j];
            float g = bn2[0 * NC + c], be = bn2[1 * NC + c];
            float mm = bn2[2 * NC + c], vv = bn2[3 * NC + c];
            float inv = g * rsqrtf(vv + EPSF);
            (pass ? GV : GK)[((size_t)b * NC + c) * HDIM + h] = t * inv + (be - mm * inv);
        }
        __syncthreads();
    }
}

// ---------------- K3: 8x8 block pool of Q -> agent tokens ----------------
__global__ __launch_bounds__(64) void k_pool(const unsigned short* __restrict__ Q,
                                             float* __restrict__ A_) {
    const int bc = blockIdx.x;
    const int ag = threadIdx.x;
    const int ph = ag >> 3, pw = ag & 7;
    const unsigned short* src = Q + (size_t)bc * NHW;
    float s = 0.f;
    #pragma unroll
    for (int i = 0; i < 8; ++i) {
        u16x8 v = *reinterpret_cast<const u16x8*>(&src[(ph * 8 + i) * WDIM + pw * 8]);
        #pragma unroll
        for (int j = 0; j < 8; ++j) s += b2f(v[j]);
    }
    A_[(size_t)bc * NAG + ag] = s * (1.0f / 64.0f);
}

// ---------------- K4a: agent attn partials (split-N flash), bf16 MFMA, gate-fused ----------------
__global__ __launch_bounds__(256) void k_attn_part(const unsigned short* __restrict__ K,
                                                   const unsigned short* __restrict__ V,
                                                   const float* __restrict__ A_,
                                                   const float* __restrict__ GK,
                                                   const float* __restrict__ GV,
                                                   float* __restrict__ Pm,
                                                   float* __restrict__ Pl,
                                                   float* __restrict__ Pacc) {
    const int bh = blockIdx.x >> 4;
    const int ns = blockIdx.x & (NSPLIT - 1);
    const int b = bh >> 3, h = bh & 7;
    const int tid = threadIdx.x;
    const int wv = tid >> 6, lane = tid & 63;
    const int lm = lane & 15, lg = lane >> 4;

    __shared__ unsigned short a_s[64 * 40];   // [ag][d]
    __shared__ unsigned short kt_s[64 * 40];  // [col][d]
    __shared__ unsigned short vt_s[32 * 72];  // [dd][col]
    __shared__ unsigned short Ps[64 * 72];    // [ag][col]

    {
        int d = tid >> 3, ag0 = (tid & 7) * 8;
        const float* ap = A_ + ((size_t)(b * NC + h * NKD + d)) * NAG + ag0;
        float4 v0 = reinterpret_cast<const float4*>(ap)[0];
        float4 v1 = reinterpret_cast<const float4*>(ap)[1];
        float t8[8] = {v0.x, v0.y, v0.z, v0.w, v1.x, v1.y, v1.z, v1.w};
        #pragma unroll
        for (int i = 0; i < 8; ++i)
            a_s[(ag0 + i) * 40 + d] = f2bf(t8[i] * FSCALE);
    }

    float mrow[4], lrow[4];
    f32x4 acc[2];
    #pragma unroll
    for (int r = 0; r < 4; ++r) { mrow[r] = -1e30f; lrow[r] = 0.f; }
    acc[0] = (f32x4){0.f, 0.f, 0.f, 0.f};
    acc[1] = (f32x4){0.f, 0.f, 0.f, 0.f};

    const int colbase = ns * (NHW / NSPLIT);
    const unsigned short* Kp = K + (size_t)(b * NC + h * NKD) * NHW + colbase;
    const unsigned short* Vp = V + (size_t)(b * NC + h * NKD) * NHW + colbase;
    const int sd = tid >> 3;
    const size_t gbase = ((size_t)(b * NC + h * NKD + sd)) * HDIM;
    __syncthreads();

    for (int nt = 0; nt < 4; ++nt) {
        const int gh = ns * 4 + nt;
        {
            int c0 = tid & 7;
            float gk = GK[gbase + gh];
            const unsigned short* kp = Kp + (size_t)sd * NHW + nt * 64 + c0;
            #pragma unroll
            for (int i = 0; i < 8; ++i)
                kt_s[(c0 + 8 * i) * 40 + sd] = f2bf(b2f(kp[8 * i]) * gk);
        }
        {
            int c0 = (tid & 7) * 8;
            float gv = GV[gbase + gh];
            const unsigned short* vp = Vp + (size_t)sd * NHW + nt * 64 + c0;
            u16x8 vr = *reinterpret_cast<const u16x8*>(vp);
            union { unsigned short u[8]; u16x8 v; } pk;
            #pragma unroll
            for (int i = 0; i < 8; ++i) pk.u[i] = f2bf(b2f(vr[i]) * gv);
            *reinterpret_cast<u16x8*>(&vt_s[sd * 72 + c0]) = pk.v;
        }
        __syncthreads();

        f32x4 s[4];
        {
            bf16x8 af = *reinterpret_cast<const bf16x8*>(&a_s[(wv * 16 + lm) * 40 + lg * 8]);
            #pragma unroll
            for (int ni = 0; ni < 4; ++ni) {
                bf16x8 kf = *reinterpret_cast<const bf16x8*>(&kt_s[(ni * 16 + lm) * 40 + lg * 8]);
                s[ni] = __builtin_amdgcn_mfma_f32_16x16x32_bf16(
                    af, kf, (f32x4){0.f, 0.f, 0.f, 0.f}, 0, 0, 0);
            }
        }

        float fsc[4];
        #pragma unroll
        for (int r = 0; r < 4; ++r) {
            float mx = fmaxf(fmaxf(s[0][r], s[1][r]), fmaxf(s[2][r], s[3][r]));
            mx = fmaxf(mx, __shfl_xor(mx, 1));
            mx = fmaxf(mx, __shfl_xor(mx, 2));
            mx = fmaxf(mx, __shfl_xor(mx, 4));
            mx = fmaxf(mx, __shfl_xor(mx, 8));
            float mnew = fmaxf(mrow[r], mx);
            fsc[r] = __expf(mrow[r] - mnew);
            mrow[r] = mnew;
            int agrow = wv * 16 + lg * 4 + r;
            float ps = 0.f;
            #pragma unroll
            for (int ni = 0; ni < 4; ++ni) {
                float p = __expf(s[ni][r] - mnew);
                Ps[agrow * 72 + ni * 16 + lm] = f2bf(p);
                ps += p;
            }
            ps += __shfl_xor(ps, 1);
            ps += __shfl_xor(ps, 2);
            ps += __shfl_xor(ps, 4);
            ps += __shfl_xor(ps, 8);
            lrow[r] = lrow[r] * fsc[r] + ps;
        }
        #pragma unroll
        for (int ni = 0; ni < 2; ++ni)
            #pragma unroll
            for (int r = 0; r < 4; ++r)
                acc[ni][r] *= fsc[r];
        __syncthreads();

        #pragma unroll
        for (int kk = 0; kk < 2; ++kk) {
            bf16x8 pa = *reinterpret_cast<const bf16x8*>(&Ps[(wv * 16 + lm) * 72 + kk * 32 + lg * 8]);
            #pragma unroll
            for (int ni = 0; ni < 2; ++ni) {
                bf16x8 vb = *reinterpret_cast<const bf16x8*>(&vt_s[(ni * 16 + lm) * 72 + kk * 32 + lg * 8]);
                acc[ni] = __builtin_amdgcn_mfma_f32_16x16x32_bf16(pa, vb, acc[ni], 0, 0, 0);
            }
        }
        __syncthreads();
    }

    const size_t pbase = (size_t)(bh * NSPLIT + ns) * NAG;
    #pragma unroll
    for (int r = 0; r < 4; ++r) {
        int ag = wv * 16 + lg * 4 + r;
        #pragma unroll
        for (int ni = 0; ni < 2; ++ni)
            Pacc[(pbase + ag) * NKD + ni * 16 + lm] = acc[ni][r];
        if (lm == 0) {
            Pm[pbase + ag] = mrow[r];
            Pl[pbase + ag] = lrow[r];
        }
    }
}

// ---------------- K4b: combine partials ----------------
__global__ __launch_bounds__(256) void k_attn_comb(const float* __restrict__ Pm,
                                                   const float* __restrict__ Pl,
                                                   const float* __restrict__ Pacc,
                                                   float* __restrict__ AT) {
    const int bh = blockIdx.x;
    const int tid = threadIdx.x;
    const int ag = tid >> 2, jg = tid & 3;
    float m = -1e30f;
    #pragma unroll
    for (int ns = 0; ns < NSPLIT; ++ns)
        m = fmaxf(m, Pm[(size_t)(bh * NSPLIT + ns) * NAG + ag]);
    float l = 0.f;
    float acc[8] = {};
    for (int ns = 0; ns < NSPLIT; ++ns) {
        size_t pb = (size_t)(bh * NSPLIT + ns) * NAG + ag;
        float f = __expf(Pm[pb] - m);
        l += Pl[pb] * f;
        const float* pp = Pacc + pb * NKD + jg * 8;
        #pragma unroll
        for (int i = 0; i < 8; ++i) acc[i] += pp[i] * f;
    }
    float linv = 1.0f / l;
    #pragma unroll
    for (int i = 0; i < 8; ++i)
        AT[((size_t)bh * NAG + ag) * NKD + jg * 8 + i] = acc[i] * linv;
}

// ---------------- K5: out1 = softmax_ag(q^T a) @ attn, bf16 MFMA, writes O1t[n][c] ----------------
__global__ __launch_bounds__(256) void k_qattn(const unsigned short* __restrict__ Q,
                                               const float* __restrict__ A_,
                                               const float* __restrict__ AT,
                                               unsigned short* __restrict__ O1t) {
    const int bh = blockIdx.y;
    const int b = bh >> 3, h = bh & 7;
    const int n0 = blockIdx.x * 128;
    const int tid = threadIdx.x;
    const int wv = tid >> 6, lane = tid & 63;
    const int lm = lane & 15, lg = lane >> 4;

    __shared__ unsigned short Qs[128][40];
    __shared__ unsigned short Ags[64][40];
    __shared__ unsigned short ATs[32][72];
    __shared__ unsigned short Ps[128][72];

    const unsigned short* Qbase = Q + ((size_t)b * NC + h * NKD) * NHW;

    {
        int d = tid >> 3, nb_ = (tid & 7) * 16;
        const unsigned short* qp = Qbase + (size_t)d * NHW + n0 + nb_;
        u16x8 v0 = *reinterpret_cast<const u16x8*>(qp);
        u16x8 v1 = *reinterpret_cast<const u16x8*>(qp + 8);
        #pragma unroll
        for (int i = 0; i < 8; ++i) Qs[nb_ + i][d] = v0[i];
        #pragma unroll
        for (int i = 0; i < 8; ++i) Qs[nb_ + 8 + i][d] = v1[i];
    }
    if (tid < 128) {
        int d = tid >> 2, ag0 = (tid & 3) * 16;
        const float* ap = A_ + ((size_t)(b * NC + h * NKD + d)) * NAG + ag0;
        #pragma unroll
        for (int i = 0; i < 16; ++i) Ags[ag0 + i][d] = f2bf(ap[i] * FSCALE);
    }
    if (tid < 128) {
        int ag = tid >> 1, d0 = (tid & 1) * 16;
        const float* atp = AT + ((size_t)bh * NAG + ag) * NKD + d0;
        #pragma unroll
        for (int i = 0; i < 16; ++i) ATs[d0 + i][ag] = f2bf(atp[i]);
    }
    __syncthreads();

    f32x4 s[2][4];
    #pragma unroll
    for (int mi = 0; mi < 2; ++mi)
        #pragma unroll
        for (int ni = 0; ni < 4; ++ni)
            s[mi][ni] = (f32x4){0.f, 0.f, 0.f, 0.f};
    {
        bf16x8 qa[2], ab[4];
        #pragma unroll
        for (int mi = 0; mi < 2; ++mi)
            qa[mi] = *reinterpret_cast<const bf16x8*>(&Qs[wv * 32 + mi * 16 + lm][lg * 8]);
        #pragma unroll
        for (int ni = 0; ni < 4; ++ni)
            ab[ni] = *reinterpret_cast<const bf16x8*>(&Ags[ni * 16 + lm][lg * 8]);
        #pragma unroll
        for (int mi = 0; mi < 2; ++mi)
            #pragma unroll
            for (int ni = 0; ni < 4; ++ni)
                s[mi][ni] = __builtin_amdgcn_mfma_f32_16x16x32_bf16(qa[mi], ab[ni], s[mi][ni], 0, 0, 0);
    }

    float lsum[2][4];
    #pragma unroll
    for (int mi = 0; mi < 2; ++mi) {
        #pragma unroll
        for (int r = 0; r < 4; ++r) {
            float mx = fmaxf(fmaxf(s[mi][0][r], s[mi][1][r]), fmaxf(s[mi][2][r], s[mi][3][r]));
            mx = fmaxf(mx, __shfl_xor(mx, 1));
            mx = fmaxf(mx, __shfl_xor(mx, 2));
            mx = fmaxf(mx, __shfl_xor(mx, 4));
            mx = fmaxf(mx, __shfl_xor(mx, 8));
            int nrow = wv * 32 + mi * 16 + lg * 4 + r;
            float ls = 0.f;
            #pragma unroll
            for (int ni = 0; ni < 4; ++ni) {
                float p = __expf(s[mi][ni][r] - mx);
                ls += p;
                Ps[nrow][ni * 16 + lm] = f2bf(p);
            }
            ls += __shfl_xor(ls, 1);
            ls += __shfl_xor(ls, 2);
            ls += __shfl_xor(ls, 4);
            ls += __shfl_xor(ls, 8);
            lsum[mi][r] = ls;
        }
    }
    __syncthreads();

    f32x4 o[2][2];
    #pragma unroll
    for (int mi = 0; mi < 2; ++mi)
        #pragma unroll
        for (int ni = 0; ni < 2; ++ni)
            o[mi][ni] = (f32x4){0.f, 0.f, 0.f, 0.f};
    #pragma unroll
    for (int kk = 0; kk < 2; ++kk) {
        bf16x8 pa[2], vb[2];
        #pragma unroll
        for (int mi = 0; mi < 2; ++mi)
            pa[mi] = *reinterpret_cast<const bf16x8*>(&Ps[wv * 32 + mi * 16 + lm][kk * 32 + lg * 8]);
        #pragma unroll
        for (int ni = 0; ni < 2; ++ni)
            vb[ni] = *reinterpret_cast<const bf16x8*>(&ATs[ni * 16 + lm][kk * 32 + lg * 8]);
        #pragma unroll
        for (int mi = 0; mi < 2; ++mi)
            #pragma unroll
            for (int ni = 0; ni < 2; ++ni)
                o[mi][ni] = __builtin_amdgcn_mfma_f32_16x16x32_bf16(pa[mi], vb[ni], o[mi][ni], 0, 0, 0);
    }

    unsigned short* obase = O1t + ((size_t)b * NHW + n0) * NC + h * NKD;
    #pragma unroll
    for (int mi = 0; mi < 2; ++mi) {
        #pragma unroll
        for (int r = 0; r < 4; ++r) {
            float rl = 1.0f / lsum[mi][r];
            int n = wv * 32 + mi * 16 + lg * 4 + r;
            #pragma unroll
            for (int ni = 0; ni < 2; ++ni) {
                int d = ni * 16 + lm;
                obase[(size_t)n * NC + d] = f2bf(o[mi][ni][r] * rl);
            }
        }
    }
}

// ---------------- K6: O1t += BN(depthwise 3x3 conv of gated V) ----------------
__global__ __launch_bounds__(256) void k_pe(const unsigned short* __restrict__ V,
                                            const float* __restrict__ GV,
                                            const float* __restrict__ wpe,
                                            const float* __restrict__ bnp,
                                            unsigned short* __restrict__ O1t) {
    const int bh_ = blockIdx.x;
    const int b = bh_ >> 6, h = bh_ & 63;
    const int tid = threadIdx.x;
    __shared__ unsigned short vs[64 * 198];
    __shared__ float gvs[64][3];
    __shared__ float wps[64][9];
    __shared__ float bns[64][2];
    const int cl = tid & 63;
    const int wq = tid >> 6;

    for (int cc = 0; cc < 4; ++cc) {
        const int cbase = cc * 64;
        #pragma unroll
        for (int j = 0; j < 6; ++j) {
            int vecid = tid + 256 * j;
            int row = vecid >> 3, seg = vecid & 7;
            int c = row / 3, kh = row - c * 3;
            int hh = h + kh - 1;
            union { unsigned short u[8]; u16x8 w; } pk;
            if (hh >= 0 && hh < HDIM) {
                pk.w = *reinterpret_cast<const u16x8*>(
                    V + ((size_t)b * NC + cbase + c) * NHW + hh * WDIM + seg * 8);
            } else {
                #pragma unroll
                for (int i = 0; i < 8; ++i) pk.u[i] = 0;
            }
            *reinterpret_cast<u16x8*>(&vs[c * 198 + kh * 66 + 1 + seg * 8]) = pk.w;
        }
        if (tid < 192) {
            int c = tid / 3, kh = tid - c * 3;
            vs[c * 198 + kh * 66 + 0] = 0;
            vs[c * 198 + kh * 66 + 65] = 0;
            int hh = h + kh - 1;
            gvs[c][kh] = (hh >= 0 && hh < HDIM)
                ? GV[((size_t)b * NC + cbase + c) * HDIM + hh] : 0.f;
        }
        for (int i = tid; i < 64 * 9; i += 256)
            wps[i / 9][i % 9] = wpe[(cbase + i / 9) * 9 + i % 9];
        if (tid < 64) {
            int c = cbase + tid;
            float g = bnp[c], be = bnp[NC + c], m = bnp[2 * NC + c], vv = bnp[3 * NC + c];
            float inv = g * rsqrtf(vv + EPSF);
            bns[tid][0] = inv;
            bns[tid][1] = be - m * inv;
        }
        __syncthreads();

        float wr[9];
        #pragma unroll
        for (int i = 0; i < 9; ++i) wr[i] = wps[cl][i];
        float g0 = gvs[cl][0], g1 = gvs[cl][1], g2 = gvs[cl][2];
        float inv = bns[cl][0], bias = bns[cl][1];
        const unsigned short* vrow = &vs[cl * 198];
        unsigned short* obase = O1t + ((size_t)b * NHW + h * WDIM) * NC + cbase + cl;
        #pragma unroll
        for (int wi = 0; wi < 16; ++wi) {
            int w = wq * 16 + wi;
            float s0 = wr[0] * b2f(vrow[0 * 66 + w]) + wr[1] * b2f(vrow[0 * 66 + w + 1]) + wr[2] * b2f(vrow[0 * 66 + w + 2]);
            float s1 = wr[3] * b2f(vrow[1 * 66 + w]) + wr[4] * b2f(vrow[1 * 66 + w + 1]) + wr[5] * b2f(vrow[1 * 66 + w + 2]);
            float s2 = wr[6] * b2f(vrow[2 * 66 + w]) + wr[7] * b2f(vrow[2 * 66 + w + 1]) + wr[8] * b2f(vrow[2 * 66 + w + 2]);
            float s = s0 * g0 + s1 * g1 + s2 * g2;
            size_t oidx = (size_t)w * NC;
            obase[oidx] = f2bf(b2f(obase[oidx]) + s * inv + bias);
        }
        __syncthreads();
    }
}

// ---------------- K7: out = BN(wpb @ O1t), bf16 MFMA, 2-phase pipelined gload_lds ----------------
__global__ __launch_bounds__(256) void k_proj(const unsigned short* __restrict__ O1t,
                                              const unsigned short* __restrict__ wb,
                                              const float* __restrict__ bnp,
                                              float* __restrict__ out) {
    const int b   = blockIdx.z;
    const int ocB = blockIdx.y * 128;
    const int nB  = blockIdx.x * 128;
    const int tid = threadIdx.x;
    const int wv  = tid >> 6, lane = tid & 63;
    const int wm = wv >> 1, wn = wv & 1;
    const int lm = lane & 15, lg = lane >> 4;

    __shared__ __align__(16) unsigned short S[2][8192];
    __shared__ float inv_s[128], bias_s[128];

    if (tid < 128) {
        int oc = ocB + tid;
        float g = bnp[0 * NC + oc], be = bnp[1 * NC + oc];
        float m = bnp[2 * NC + oc], vv = bnp[3 * NC + oc];
        float inv = g * rsqrtf(vv + EPSF);
        inv_s[tid] = inv;
        bias_s[tid] = be - m * inv;
    }

    f32x4 acc[4][4];
    #pragma unroll
    for (int i = 0; i < 4; ++i)
        #pragma unroll
        for (int j = 0; j < 4; ++j)
            acc[i][j] = (f32x4){0.f, 0.f, 0.f, 0.f};

    const int srow = lane >> 2;
    const int kl = ((lane & 3) ^ ((lane >> 3) & 3)) * 8;
    const size_t agbase = (size_t)(ocB + wv * 32 + srow) * 256 + kl;
    const size_t bgbase = ((size_t)b * NHW + nB + wv * 32 + srow) * NC + kl;
    const int sw = (lm >> 1) & 3;

    auto STAGE = [&](int buf, int k0) {
        #pragma unroll
        for (int j = 0; j < 2; ++j) {
            gload_lds16(wb + agbase + (size_t)j * 16 * 256 + k0, &S[buf][wv * 1024 + j * 512]);
            gload_lds16(O1t + bgbase + (size_t)j * 16 * NC + k0, &S[buf][4096 + wv * 1024 + j * 512]);
        }
    };

    STAGE(0, 0);
    asm volatile("s_waitcnt vmcnt(0)" ::: "memory");
    __builtin_amdgcn_s_barrier();
    __builtin_amdgcn_sched_barrier(0);

    int cur = 0;
    for (int t = 0; t < 8; ++t) {
        if (t < 7) STAGE(cur ^ 1, (t + 1) * 32);

        const unsigned short* As = &S[cur][0];
        const unsigned short* Bs = &S[cur][4096];
        bf16x8 af[4], bfr[4];
        #pragma unroll
        for (int mi = 0; mi < 4; ++mi)
            af[mi] = *reinterpret_cast<const bf16x8*>(&As[(wm * 64 + mi * 16 + lm) * 32 + (lg ^ sw) * 8]);
        #pragma unroll
        for (int ni = 0; ni < 4; ++ni)
            bfr[ni] = *reinterpret_cast<const bf16x8*>(&Bs[(wn * 64 + ni * 16 + lm) * 32 + (lg ^ sw) * 8]);
        #pragma unroll
        for (int mi = 0; mi < 4; ++mi)
            #pragma unroll
            for (int ni = 0; ni < 4; ++ni)
                acc[mi][ni] = __builtin_amdgcn_mfma_f32_16x16x32_bf16(af[mi], bfr[ni], acc[mi][ni], 0, 0, 0);

        if (t < 7) {
            asm volatile("s_waitcnt vmcnt(0)" ::: "memory");
            __builtin_amdgcn_s_barrier();
            __builtin_amdgcn_sched_barrier(0);
            cur ^= 1;
        }
    }

    float* dstb = out + ((size_t)b * NC + ocB) * NHW + nB;
    #pragma unroll
    for (int mi = 0; mi < 4; ++mi) {
        int lo_base = wm * 64 + mi * 16 + lg * 4;
        #pragma unroll
        for (int r = 0; r < 4; ++r) {
            int lo = lo_base + r;
            float inv = inv_s[lo], bias = bias_s[lo];
            #pragma unroll
            for (int ni = 0; ni < 4; ++ni) {
                int n = wn * 64 + ni * 16 + lm;
                dstb[(size_t)lo * NHW + n] = acc[mi][ni][r] * inv + bias;
            }
        }
    }
}

extern "C" void kernel_launch(void* const* d_in, const int* in_sizes, int n_in,
                              void* d_out, int out_size, void* d_ws, size_t ws_size,
                              hipStream_t stream) {
    (void)in_sizes; (void)n_in; (void)out_size; (void)ws_size;
    const float* x       = (const float*)d_in[0];
    const float* w_qkv   = (const float*)d_in[1];
    const float* bn_qkv  = (const float*)d_in[2];
    const float* w_cv1   = (const float*)d_in[3];
    const float* bn_cv1  = (const float*)d_in[4];
    const float* w_cv2   = (const float*)d_in[5];
    const float* bn_cv2  = (const float*)d_in[6];
    const float* w_proj  = (const float*)d_in[7];
    const float* bn_proj = (const float*)d_in[8];
    const float* w_pe    = (const float*)d_in[9];
    const float* bn_pe   = (const float*)d_in[10];
    float* out = (float*)d_out;

    unsigned short* Qb  = (unsigned short*)d_ws;
    unsigned short* Kb  = Qb + SZQ;
    unsigned short* Vb  = Kb + SZQ;
    unsigned short* O1t = Vb + SZQ;
    unsigned short* xbt = O1t + SZQ;                    // SZQ bf16
    unsigned short* wqb = xbt + SZQ;                    // 196608
    unsigned short* wpb = wqb + 768 * 256;              // 65536
    float* Aa   = (float*)(wpb + 65536);
    float* AT   = Aa + (size_t)NB * NC * NAG;               // 131072
    float* Pm   = AT + (size_t)NB * NHEAD * NAG * NKD;      // 131072
    float* Pl   = Pm + (size_t)NB * NHEAD * NSPLIT * NAG;   // 65536
    float* Pacc = Pl + (size_t)NB * NHEAD * NSPLIT * NAG;   // 65536
    float* AMK  = Pacc + (size_t)NB * NHEAD * NSPLIT * NAG * NKD;  // 2.1M
    float* AMV  = AMK + (size_t)NB * HDIM * NC;             // 131072
    float* GK   = AMV + (size_t)NB * HDIM * NC;
    float* GV   = GK + (size_t)NB * NC * HDIM;

    k_xpose<<<dim3(64, NB), 256, 0, stream>>>(x, xbt);
    k_wcast<<<256, 256, 0, stream>>>(w_qkv, w_proj, wqb, wpb);
    k_qkv<<<dim3(32, 6, NB), 256, 0, stream>>>(xbt, wqb, bn_qkv, Qb, Kb, Vb, AMK, AMV);
    k_gatecomp<<<NB * HDIM, 256, 0, stream>>>(AMK, AMV, w_cv1, bn_cv1, w_cv2, bn_cv2, GK, GV);
    k_pool<<<NB * NC, 64, 0, stream>>>(Qb, Aa);
    k_attn_part<<<NB * NHEAD * NSPLIT, 256, 0, stream>>>(Kb, Vb, Aa, GK, GV, Pm, Pl, Pacc);
    k_attn_comb<<<NB * NHEAD, 256, 0, stream>>>(Pm, Pl, Pacc, AT);
    k_qattn<<<dim3(32, 64), 256, 0, stream>>>(Qb, Aa, AT, O1t);
    k_pe<<<NB * HDIM, 256, 0, stream>>>(Vb, GV, w_pe, bn_pe, O1t);
    k_proj<<<dim3(32, 2, NB), 256, 0, stream>>>(O1t, wpb, bn_proj, out);
}